// Round 5
// baseline (1220.506 us; speedup 1.0000x reference)
//
#include <hip/hip_runtime.h>
#include <hip/hip_bf16.h>

#define HD 128   // hidden size

typedef __attribute__((ext_vector_type(8))) short bf16x8;
typedef __attribute__((ext_vector_type(4))) float f32x4;

__device__ __forceinline__ ushort f2bf(float f) {
    uint u = __float_as_uint(f);
    return (ushort)((u + 0x7FFFu + ((u >> 16) & 1u)) >> 16);
}
__device__ __forceinline__ float bf2f(ushort h) {
    return __uint_as_float(((uint)h) << 16);
}

// ---------------- encoder: h = x @ W_enc + b_enc (no activation) ----------------
__global__ __launch_bounds__(256) void encoder_kernel(
    const float* __restrict__ x, const float* __restrict__ W,
    const float* __restrict__ b, float* __restrict__ h, int N)
{
    int n = blockIdx.x * 2 + (threadIdx.x >> 7);
    int c = threadIdx.x & 127;
    if (n >= N) return;
    const float* xr = x + (size_t)n * 16;
    float acc = b[c];
#pragma unroll
    for (int k = 0; k < 16; ++k)
        acc = fmaf(xr[k], W[k * HD + c], acc);
    h[(size_t)n * HD + c] = acc;
}

// ---------------- int degree histogram ----------------
__global__ __launch_bounds__(256) void deg_int_kernel(
    const int* __restrict__ dst, int* __restrict__ deg, int E)
{
    int e = blockIdx.x * 256 + threadIdx.x;
    if (e < E) atomicAdd(&deg[dst[e]], 1);
}

// r = 1/max(cnt,1), s = cnt/max(cnt,1)
__global__ __launch_bounds__(256) void degscale_kernel(
    const int* __restrict__ deg, float* __restrict__ r,
    float* __restrict__ s, int N)
{
    int n = blockIdx.x * 256 + threadIdx.x;
    if (n < N) {
        float c = (float)deg[n];
        float cp = fmaxf(c, 1.0f);
        r[n] = 1.0f / cp;
        s[n] = c / cp;
    }
}

// ---------------- single-block exclusive scan: off[0..N], off[N]=total ----------------
__global__ __launch_bounds__(256) void scan_kernel(
    const int* __restrict__ deg, int* __restrict__ off, int N)
{
    __shared__ int wsum[4];
    const int tid = threadIdx.x;
    const int lane = tid & 63;
    const int wid = tid >> 6;
    int carry = 0;
    for (int base = 0; base < N; base += 256) {
        int i = base + tid;
        int v = (i < N) ? deg[i] : 0;
        int x = v;
#pragma unroll
        for (int d = 1; d < 64; d <<= 1) {
            int y = __shfl_up(x, d);
            if (lane >= d) x += y;
        }
        if (lane == 63) wsum[wid] = x;
        __syncthreads();
        int add = 0;
#pragma unroll
        for (int w = 0; w < 3; ++w)
            if (w < wid) add += wsum[w];
        if (i < N) off[i] = carry + add + x - v;   // exclusive prefix
        carry += wsum[0] + wsum[1] + wsum[2] + wsum[3];
        __syncthreads();
    }
    if (tid == 0) off[N] = carry;
}

// ---------------- CSR fill: slot -> (src, dst, eid) ----------------
__global__ __launch_bounds__(256) void csr_fill_kernel(
    const int* __restrict__ src, const int* __restrict__ dst,
    const int* __restrict__ off, int* __restrict__ cursor,
    int* __restrict__ csr_src, int* __restrict__ csr_dst,
    int* __restrict__ csr_eid, int E)
{
    int e = blockIdx.x * 256 + threadIdx.x;
    if (e < E) {
        int d = dst[e];
        int p = atomicAdd(&cursor[d], 1);
        int pos = off[d] + p;
        csr_src[pos] = src[e];
        csr_dst[pos] = d;
        csr_eid[pos] = e;
    }
}

// ---------------- pull aggregation: S[n] = r[n] * sum_{e:dst=n} h[src_e] ----------------
__global__ __launch_bounds__(256) void pull_kernel(
    const float* __restrict__ h, const int* __restrict__ off,
    const int* __restrict__ csr, const float* __restrict__ r,
    float* __restrict__ S, int N)
{
    int n = blockIdx.x * 4 + (threadIdx.x >> 6);
    if (n >= N) return;
    int lane = threadIdx.x & 63;
    int beg = off[n], end = off[n + 1];
    float ax = 0.0f, ay = 0.0f;
    for (int i = beg; i < end; ++i) {
        int s = csr[i];
        float2 v = *reinterpret_cast<const float2*>(h + (size_t)s * HD + 2 * lane);
        ax += v.x; ay += v.y;
    }
    float rr = r[n];
    *reinterpret_cast<float2*>(S + (size_t)n * HD + 2 * lane) =
        make_float2(ax * rr, ay * rr);
}

// ---------------- W[K][C] -> transposed bf16 hi/lo: WT[c][k] ----------------
__global__ __launch_bounds__(256) void wt_convert_kernel(
    const float* __restrict__ W, ushort* __restrict__ WThi,
    ushort* __restrict__ WTlo, int K, int C)
{
    int idx = blockIdx.x * 256 + threadIdx.x;
    if (idx >= K * C) return;
    int k = idx / C, c = idx % C;
    float a = W[idx];
    ushort hi = f2bf(a);
    ushort lo = f2bf(a - bf2f(hi));
    WThi[c * K + k] = hi;
    WTlo[c * K + k] = lo;
}

// ---------------- split-bf16 MFMA GEMM: out[N,128] = A[N,K] @ W[K,128] ----------------
// A = [A0 | s1*A1] rowwise (K=256) or A0 (K=128). out = A@W + bscale*bias, opt relu.
// W transposed bf16 hi/lo, read directly from L2 (no LDS staging).
// Ping-pong A LDS buffer, 1 barrier/step.
__global__ __launch_bounds__(256) void gemm_mfma_kernel(
    const float* __restrict__ A0, const float* __restrict__ A1,
    const float* __restrict__ s1,
    const ushort* __restrict__ WT_hi, const ushort* __restrict__ WT_lo,
    int wstride, int kw0,
    const float* __restrict__ bias, const float* __restrict__ bscale,
    float* __restrict__ out, int N, int K, int relu)
{
    __shared__ __align__(16) ushort Ahi_s[2][64][40];
    __shared__ __align__(16) ushort Alo_s[2][64][40];

    const int tid    = threadIdx.x;
    const int n_base = blockIdx.x * 64;
    const int sa_row = tid >> 2;            // 0..63
    const int sa_k4  = (tid & 3) * 4;       // 0,4,8,12
    const int sa_ng  = min(n_base + sa_row, N - 1);
    const float scA1 = s1 ? s1[sa_ng] : 1.0f;
    const int lane = tid & 63, wv = tid >> 6;
    const int fr = lane & 15;
    const int fk = (lane >> 4) * 8;

    f32x4 acc[8];
#pragma unroll
    for (int t = 0; t < 8; ++t) acc[t] = (f32x4){0.f, 0.f, 0.f, 0.f};

    const int nsteps = K >> 5;
    for (int s = 0; s < nsteps; ++s) {
        const int k0 = s * 32;
        const int pp = s & 1;
        // ---- stage A (f32 -> hi/lo bf16) ----
        const float* Ab; int kof; float sc;
        if (K == 256 && k0 >= 128) { Ab = A1; kof = k0 - 128; sc = scA1; }
        else                       { Ab = A0; kof = k0;       sc = 1.0f; }
#pragma unroll
        for (int ch = 0; ch < 32; ch += 16) {
            float4 v = *reinterpret_cast<const float4*>(
                Ab + (size_t)sa_ng * HD + kof + ch + sa_k4);
            float vv[4] = {v.x * sc, v.y * sc, v.z * sc, v.w * sc};
            ushort4 hi, lo;
            hi.x = f2bf(vv[0]); lo.x = f2bf(vv[0] - bf2f(hi.x));
            hi.y = f2bf(vv[1]); lo.y = f2bf(vv[1] - bf2f(hi.y));
            hi.z = f2bf(vv[2]); lo.z = f2bf(vv[2] - bf2f(hi.z));
            hi.w = f2bf(vv[3]); lo.w = f2bf(vv[3] - bf2f(hi.w));
            *reinterpret_cast<ushort4*>(&Ahi_s[pp][sa_row][ch + sa_k4]) = hi;
            *reinterpret_cast<ushort4*>(&Alo_s[pp][sa_row][ch + sa_k4]) = lo;
        }
        __syncthreads();
        // ---- MFMA: 8 col-tiles x 3 products; B frags straight from L2 ----
        bf16x8 ah = *reinterpret_cast<bf16x8*>(&Ahi_s[pp][wv * 16 + fr][fk]);
        bf16x8 al = *reinterpret_cast<bf16x8*>(&Alo_s[pp][wv * 16 + fr][fk]);
#pragma unroll
        for (int t = 0; t < 8; ++t) {
            const size_t boff = (size_t)(t * 16 + fr) * wstride + kw0 + k0 + fk;
            bf16x8 bh = *reinterpret_cast<const bf16x8*>(WT_hi + boff);
            bf16x8 bl = *reinterpret_cast<const bf16x8*>(WT_lo + boff);
            acc[t] = __builtin_amdgcn_mfma_f32_16x16x32_bf16(ah, bh, acc[t], 0, 0, 0);
            acc[t] = __builtin_amdgcn_mfma_f32_16x16x32_bf16(al, bh, acc[t], 0, 0, 0);
            acc[t] = __builtin_amdgcn_mfma_f32_16x16x32_bf16(ah, bl, acc[t], 0, 0, 0);
        }
    }
    // ---- epilogue: C/D map col=lane&15, row=(lane>>4)*4+reg ----
#pragma unroll
    for (int reg = 0; reg < 4; ++reg) {
        int n = n_base + wv * 16 + (lane >> 4) * 4 + reg;
        if (n < N) {
            float bs = bscale ? bscale[n] : 1.0f;
#pragma unroll
            for (int t = 0; t < 8; ++t) {
                int c = t * 16 + fr;
                float v = acc[t][reg] + (bias ? bias[c] * bs : 0.0f);
                out[(size_t)n * HD + c] = relu ? fmaxf(v, 0.0f) : v;
            }
        }
    }
}

// ---------------- node head: relu(h@Wn1+bn1)@Wn2+bn2 ----------------
__global__ __launch_bounds__(256) void node_head_kernel(
    const float* __restrict__ h,
    const float* __restrict__ W1, const float* __restrict__ b1,
    const float* __restrict__ W2, const float* __restrict__ b2,
    float* __restrict__ out, int N)
{
    int n = blockIdx.x * 4 + (threadIdx.x >> 6);
    int lane = threadIdx.x & 63;
    if (n >= N) return;
    const float* hr = h + (size_t)n * HD;
    float t = b1[lane];
#pragma unroll 16
    for (int k = 0; k < HD; ++k)
        t = fmaf(hr[k], W1[k * 64 + lane], t);
    t = fmaxf(t, 0.0f);
    float o0 = t * W2[lane * 2 + 0];
    float o1 = t * W2[lane * 2 + 1];
#pragma unroll
    for (int sft = 32; sft > 0; sft >>= 1) {
        o0 += __shfl_xor(o0, sft);
        o1 += __shfl_xor(o1, sft);
    }
    if (lane == 0) {
        out[(size_t)n * 2 + 0] = o0 + b2[0];
        out[(size_t)n * 2 + 1] = o1 + b2[1];
    }
}

// ---------------- fused edge head, CSR-ordered, MFMA phase 2 ----------------
// slot i: (s,d,eid). t1 = relu(P[s]+Q[d]+ea[eid]@W1c+b1)  (split-bf16 in LDS)
// t2 = relu(t1@W2+b2) via MFMA; out[eid] = t2@W3+b3 via in-register reduce.
__global__ __launch_bounds__(256) void edge_head_kernel(
    const float* __restrict__ P, const float* __restrict__ Q,
    const int* __restrict__ csr_src, const int* __restrict__ csr_dst,
    const int* __restrict__ csr_eid,
    const float* __restrict__ ea,
    const float* __restrict__ W1c, const float* __restrict__ b1,
    const ushort* __restrict__ W2Th, const ushort* __restrict__ W2Tl,  // [64][128]
    const float* __restrict__ b2,
    const float* __restrict__ W3, const float* __restrict__ b3,
    float* __restrict__ out, int E)
{
    __shared__ __align__(16) ushort t1h_s[64][132];
    __shared__ __align__(16) ushort t1l_s[64][132];
    __shared__ int eid_s[64];

    const int tid  = threadIdx.x;
    const int base = blockIdx.x * 64;

    // ---- phase 1: build t1 (hi/lo bf16) ----
    {
        int e    = tid & 63;
        int ch   = tid >> 6;                       // 0..3, 32 cols each
        int slot = min(base + e, E - 1);
        int sn = csr_src[slot], dn = csr_dst[slot], eid = csr_eid[slot];
        if (ch == 0) eid_s[e] = eid;
        const float* Pr = P + (size_t)sn * HD + ch * 32;
        const float* Qr = Q + (size_t)dn * HD + ch * 32;
        float eav[8];
#pragma unroll
        for (int k = 0; k < 8; ++k) eav[k] = ea[(size_t)eid * 8 + k];
#pragma unroll
        for (int j = 0; j < 32; j += 4) {
            int c = ch * 32 + j;
            float4 p  = *reinterpret_cast<const float4*>(Pr + j);
            float4 q  = *reinterpret_cast<const float4*>(Qr + j);
            float4 bb = *reinterpret_cast<const float4*>(b1 + c);
            float v0 = p.x + q.x + bb.x;
            float v1 = p.y + q.y + bb.y;
            float v2 = p.z + q.z + bb.z;
            float v3 = p.w + q.w + bb.w;
#pragma unroll
            for (int k = 0; k < 8; ++k) {
                float4 w = *reinterpret_cast<const float4*>(W1c + k * HD + c);
                v0 = fmaf(eav[k], w.x, v0);
                v1 = fmaf(eav[k], w.y, v1);
                v2 = fmaf(eav[k], w.z, v2);
                v3 = fmaf(eav[k], w.w, v3);
            }
            v0 = fmaxf(v0, 0.0f); v1 = fmaxf(v1, 0.0f);
            v2 = fmaxf(v2, 0.0f); v3 = fmaxf(v3, 0.0f);
            ushort4 hi, lo;
            hi.x = f2bf(v0); lo.x = f2bf(v0 - bf2f(hi.x));
            hi.y = f2bf(v1); lo.y = f2bf(v1 - bf2f(hi.y));
            hi.z = f2bf(v2); lo.z = f2bf(v2 - bf2f(hi.z));
            hi.w = f2bf(v3); lo.w = f2bf(v3 - bf2f(hi.w));
            *reinterpret_cast<ushort4*>(&t1h_s[e][c]) = hi;
            *reinterpret_cast<ushort4*>(&t1l_s[e][c]) = lo;
        }
    }
    __syncthreads();

    // ---- phase 2: t2 = relu(t1 @ W2 + b2), MFMA; wave wv owns edges [wv*16, wv*16+16) ----
    const int lane = tid & 63, wv = tid >> 6;
    const int fr = lane & 15;
    const int fk = (lane >> 4) * 8;
    f32x4 acc[4];
#pragma unroll
    for (int t = 0; t < 4; ++t) acc[t] = (f32x4){0.f, 0.f, 0.f, 0.f};
#pragma unroll
    for (int kt = 0; kt < 4; ++kt) {
        bf16x8 ah = *reinterpret_cast<bf16x8*>(&t1h_s[wv * 16 + fr][kt * 32 + fk]);
        bf16x8 al = *reinterpret_cast<bf16x8*>(&t1l_s[wv * 16 + fr][kt * 32 + fk]);
#pragma unroll
        for (int t = 0; t < 4; ++t) {
            const size_t boff = (size_t)(t * 16 + fr) * 128 + kt * 32 + fk;
            bf16x8 bh = *reinterpret_cast<const bf16x8*>(W2Th + boff);
            bf16x8 bl = *reinterpret_cast<const bf16x8*>(W2Tl + boff);
            acc[t] = __builtin_amdgcn_mfma_f32_16x16x32_bf16(ah, bh, acc[t], 0, 0, 0);
            acc[t] = __builtin_amdgcn_mfma_f32_16x16x32_bf16(al, bh, acc[t], 0, 0, 0);
            acc[t] = __builtin_amdgcn_mfma_f32_16x16x32_bf16(ah, bl, acc[t], 0, 0, 0);
        }
    }

    // ---- phase 3: out = relu(t2+b2) @ W3 + b3, in registers ----
    // C/D map: col = t*16+fr, edge-row = wv*16 + (lane>>4)*4 + reg.
    float b2v[4];
#pragma unroll
    for (int t = 0; t < 4; ++t) b2v[t] = b2[t * 16 + fr];
#pragma unroll
    for (int reg = 0; reg < 4; ++reg) {
        int erow = wv * 16 + (lane >> 4) * 4 + reg;
        float p[6];
#pragma unroll
        for (int j = 0; j < 6; ++j) p[j] = 0.0f;
#pragma unroll
        for (int t = 0; t < 4; ++t) {
            int c = t * 16 + fr;
            float t2v = fmaxf(acc[t][reg] + b2v[t], 0.0f);
#pragma unroll
            for (int j = 0; j < 6; ++j)
                p[j] = fmaf(t2v, W3[c * 6 + j], p[j]);
        }
#pragma unroll
        for (int j = 0; j < 6; ++j) {
#pragma unroll
            for (int sft = 1; sft < 16; sft <<= 1)
                p[j] += __shfl_xor(p[j], sft);
        }
        int slot = base + erow;
        if (fr < 6 && slot < E) {
            int eid = eid_s[erow];
            out[(size_t)eid * 6 + fr] = p[fr] + b3[fr];
        }
    }
}

// ---------------- launch ----------------
extern "C" void kernel_launch(void* const* d_in, const int* in_sizes, int n_in,
                              void* d_out, int out_size, void* d_ws, size_t ws_size,
                              hipStream_t stream)
{
    (void)n_in; (void)out_size; (void)ws_size;
    const float* x     = (const float*)d_in[0];
    const int*   ei    = (const int*)d_in[1];
    const float* eattr = (const float*)d_in[2];
    const float* Wenc = (const float*)d_in[4];
    const float* benc = (const float*)d_in[5];
    const float* Wmsg = (const float*)d_in[6];
    const float* bmsg = (const float*)d_in[7];
    const float* Wupd = (const float*)d_in[8];
    const float* bupd = (const float*)d_in[9];
    const float* Wn1  = (const float*)d_in[10];
    const float* bn1  = (const float*)d_in[11];
    const float* Wn2  = (const float*)d_in[12];
    const float* bn2  = (const float*)d_in[13];
    const float* We1  = (const float*)d_in[14];
    const float* be1  = (const float*)d_in[15];
    const float* We2  = (const float*)d_in[16];
    const float* be2  = (const float*)d_in[17];
    const float* We3  = (const float*)d_in[18];
    const float* be3  = (const float*)d_in[19];

    const int N = in_sizes[0] / 16;
    const int E = in_sizes[1] / 2;
    const int* src = ei;
    const int* dst = ei + E;

    float* h0   = (float*)d_ws;
    float* h1   = h0 + (size_t)N * HD;
    float* S    = h1 + (size_t)N * HD;     // pull target; later reused as P
    float* agg  = S  + (size_t)N * HD;     // agg; later reused as Q
    float* rs   = agg + (size_t)N * HD;
    float* ss   = rs + N;
    int* deg_i  = (int*)(ss + N);
    int* off    = deg_i + N;               // N+1
    int* cursor = off + N + 1;
    int* csr_s  = cursor + N;              // E
    int* csr_d  = csr_s + E;               // E
    int* csr_e  = csr_d + E;               // E
    ushort* wt  = (ushort*)(((uintptr_t)(csr_e + E) + 255) & ~(uintptr_t)255);
    ushort* wtm_hi = wt;                   // 128*256 each
    ushort* wtm_lo = wtm_hi + 32768;
    ushort* wtu_hi = wtm_lo + 32768;
    ushort* wtu_lo = wtu_hi + 32768;
    ushort* wte_hi = wtu_lo + 32768;
    ushort* wte_lo = wte_hi + 32768;
    ushort* w2t_hi = wte_lo + 32768;       // 64*128 each
    ushort* w2t_lo = w2t_hi + 8192;

    float* node_out = (float*)d_out;
    float* edge_out = node_out + (size_t)N * 2;

    // ---- CSR build ----
    hipMemsetAsync(deg_i, 0, (size_t)N * sizeof(int), stream);
    hipMemsetAsync(cursor, 0, (size_t)N * sizeof(int), stream);
    deg_int_kernel<<<(E + 255) / 256, 256, 0, stream>>>(dst, deg_i, E);
    scan_kernel<<<1, 256, 0, stream>>>(deg_i, off, N);
    degscale_kernel<<<(N + 255) / 256, 256, 0, stream>>>(deg_i, rs, ss, N);
    csr_fill_kernel<<<(E + 255) / 256, 256, 0, stream>>>(
        src, dst, off, cursor, csr_s, csr_d, csr_e, E);

    // ---- weight prep: transposed bf16 hi/lo ----
    wt_convert_kernel<<<128, 256, 0, stream>>>(Wmsg, wtm_hi, wtm_lo, 256, 128);
    wt_convert_kernel<<<128, 256, 0, stream>>>(Wupd, wtu_hi, wtu_lo, 256, 128);
    wt_convert_kernel<<<128, 256, 0, stream>>>(We1,  wte_hi, wte_lo, 256, 128);
    wt_convert_kernel<<<32,  256, 0, stream>>>(We2,  w2t_hi, w2t_lo, 128, 64);

    // ---- encoder ----
    encoder_kernel<<<(N + 1) / 2, 256, 0, stream>>>(x, Wenc, benc, h0, N);

    // ---- GNN layers ----
    const int gblocks = (N + 63) / 64;
    float* hc = h0;
    float* hn = h1;
    for (int l = 0; l < 3; ++l) {
        pull_kernel<<<(N + 3) / 4, 256, 0, stream>>>(hc, off, csr_s, rs, S, N);
        gemm_mfma_kernel<<<gblocks, 256, 0, stream>>>(
            S, hc, ss, wtm_hi, wtm_lo, 256, 0, bmsg, ss, agg, N, 256, 0);
        gemm_mfma_kernel<<<gblocks, 256, 0, stream>>>(
            hc, agg, nullptr, wtu_hi, wtu_lo, 256, 0, bupd, nullptr, hn, N, 256, 1);
        float* t = hc; hc = hn; hn = t;
    }

    // ---- P/Q precompute for edge head ----
    float* Pb = S;
    float* Qb = agg;
    gemm_mfma_kernel<<<gblocks, 256, 0, stream>>>(
        hc, nullptr, nullptr, wte_hi, wte_lo, 256, 0, nullptr, nullptr, Pb, N, 128, 0);
    gemm_mfma_kernel<<<gblocks, 256, 0, stream>>>(
        hc, nullptr, nullptr, wte_hi, wte_lo, 256, 128, nullptr, nullptr, Qb, N, 128, 0);

    // ---- heads ----
    node_head_kernel<<<(N + 3) / 4, 256, 0, stream>>>(
        hc, Wn1, bn1, Wn2, bn2, node_out, N);
    edge_head_kernel<<<(E + 63) / 64, 256, 0, stream>>>(
        Pb, Qb, csr_s, csr_d, csr_e, eattr, We1 + (size_t)256 * HD, be1,
        w2t_hi, w2t_lo, be2, We3, be3, edge_out, E);
}

// Round 6
// 977.016 us; speedup vs baseline: 1.2492x; 1.2492x over previous
//
#include <hip/hip_runtime.h>
#include <hip/hip_bf16.h>

#define HD 128   // hidden size

typedef __attribute__((ext_vector_type(8))) short bf16x8;
typedef __attribute__((ext_vector_type(4))) float f32x4;

__device__ __forceinline__ ushort f2bf(float f) {
    uint u = __float_as_uint(f);
    return (ushort)((u + 0x7FFFu + ((u >> 16) & 1u)) >> 16);
}
__device__ __forceinline__ float bf2f(ushort h) {
    return __uint_as_float(((uint)h) << 16);
}

// ---------------- encoder: h = x @ W_enc + b_enc (no activation) ----------------
__global__ __launch_bounds__(256) void encoder_kernel(
    const float* __restrict__ x, const float* __restrict__ W,
    const float* __restrict__ b, float* __restrict__ h, int N)
{
    int n = blockIdx.x * 2 + (threadIdx.x >> 7);
    int c = threadIdx.x & 127;
    if (n >= N) return;
    const float* xr = x + (size_t)n * 16;
    float acc = b[c];
#pragma unroll
    for (int k = 0; k < 16; ++k)
        acc = fmaf(xr[k], W[k * HD + c], acc);
    h[(size_t)n * HD + c] = acc;
}

// ---------------- int degree histogram ----------------
__global__ __launch_bounds__(256) void deg_int_kernel(
    const int* __restrict__ dst, int* __restrict__ deg, int E)
{
    int e = blockIdx.x * 256 + threadIdx.x;
    if (e < E) atomicAdd(&deg[dst[e]], 1);
}

// r = 1/max(cnt,1), s = cnt/max(cnt,1)
__global__ __launch_bounds__(256) void degscale_kernel(
    const int* __restrict__ deg, float* __restrict__ r,
    float* __restrict__ s, int N)
{
    int n = blockIdx.x * 256 + threadIdx.x;
    if (n < N) {
        float c = (float)deg[n];
        float cp = fmaxf(c, 1.0f);
        r[n] = 1.0f / cp;
        s[n] = c / cp;
    }
}

// ---------------- single-block exclusive scan: off[0..N], off[N]=total ----------------
__global__ __launch_bounds__(256) void scan_kernel(
    const int* __restrict__ deg, int* __restrict__ off, int N)
{
    __shared__ int wsum[4];
    const int tid = threadIdx.x;
    const int lane = tid & 63;
    const int wid = tid >> 6;
    int carry = 0;
    for (int base = 0; base < N; base += 256) {
        int i = base + tid;
        int v = (i < N) ? deg[i] : 0;
        int x = v;
#pragma unroll
        for (int d = 1; d < 64; d <<= 1) {
            int y = __shfl_up(x, d);
            if (lane >= d) x += y;
        }
        if (lane == 63) wsum[wid] = x;
        __syncthreads();
        int add = 0;
#pragma unroll
        for (int w = 0; w < 3; ++w)
            if (w < wid) add += wsum[w];
        if (i < N) off[i] = carry + add + x - v;   // exclusive prefix
        carry += wsum[0] + wsum[1] + wsum[2] + wsum[3];
        __syncthreads();
    }
    if (tid == 0) off[N] = carry;
}

// ---------------- CSR fill: slot -> (src, dst, eid) ----------------
__global__ __launch_bounds__(256) void csr_fill_kernel(
    const int* __restrict__ src, const int* __restrict__ dst,
    const int* __restrict__ off, int* __restrict__ cursor,
    int* __restrict__ csr_src, int* __restrict__ csr_dst,
    int* __restrict__ csr_eid, int E)
{
    int e = blockIdx.x * 256 + threadIdx.x;
    if (e < E) {
        int d = dst[e];
        int p = atomicAdd(&cursor[d], 1);
        int pos = off[d] + p;
        csr_src[pos] = src[e];
        csr_dst[pos] = d;
        csr_eid[pos] = e;
    }
}

// ---------------- pull aggregation: S[n] = r[n] * sum_{e:dst=n} h[src_e] ----------------
__global__ __launch_bounds__(256) void pull_kernel(
    const float* __restrict__ h, const int* __restrict__ off,
    const int* __restrict__ csr, const float* __restrict__ r,
    float* __restrict__ S, int N)
{
    int n = blockIdx.x * 4 + (threadIdx.x >> 6);
    if (n >= N) return;
    int lane = threadIdx.x & 63;
    int beg = off[n], end = off[n + 1];
    float ax = 0.0f, ay = 0.0f;
    for (int i = beg; i < end; ++i) {
        int s = csr[i];
        float2 v = *reinterpret_cast<const float2*>(h + (size_t)s * HD + 2 * lane);
        ax += v.x; ay += v.y;
    }
    float rr = r[n];
    *reinterpret_cast<float2*>(S + (size_t)n * HD + 2 * lane) =
        make_float2(ax * rr, ay * rr);
}

// ---------------- W[K][C] -> transposed bf16 hi/lo: WT[c][k] ----------------
__global__ __launch_bounds__(256) void wt_convert_kernel(
    const float* __restrict__ W, ushort* __restrict__ WThi,
    ushort* __restrict__ WTlo, int K, int C)
{
    int idx = blockIdx.x * 256 + threadIdx.x;
    if (idx >= K * C) return;
    int k = idx / C, c = idx % C;
    float a = W[idx];
    ushort hi = f2bf(a);
    ushort lo = f2bf(a - bf2f(hi));
    WThi[c * K + k] = hi;
    WTlo[c * K + k] = lo;
}

// ---------------- split-bf16 MFMA GEMM: out[N,128] = A[N,K] @ W[K,128] ----------------
// (round-4 proven version: A and B staged in LDS, 2 barriers/step)
__global__ __launch_bounds__(256) void gemm_mfma_kernel(
    const float* __restrict__ A0, const float* __restrict__ A1,
    const float* __restrict__ s1,
    const ushort* __restrict__ WT_hi, const ushort* __restrict__ WT_lo,
    int wstride, int kw0,
    const float* __restrict__ bias, const float* __restrict__ bscale,
    float* __restrict__ out, int N, int K, int relu)
{
    __shared__ __align__(16) ushort Ahi_s[64][40];
    __shared__ __align__(16) ushort Alo_s[64][40];
    __shared__ __align__(16) ushort Bhi_s[128][40];
    __shared__ __align__(16) ushort Blo_s[128][40];

    const int tid    = threadIdx.x;
    const int n_base = blockIdx.x * 64;
    const int sa_row = tid >> 2;            // 0..63
    const int sa_k4  = (tid & 3) * 4;       // 0,4,8,12
    const int sa_ng  = min(n_base + sa_row, N - 1);
    const float scA1 = s1 ? s1[sa_ng] : 1.0f;
    const int sb_c = tid & 127;
    const int sb_h = (tid >> 7) * 16;       // 0 or 16
    const int lane = tid & 63, wv = tid >> 6;
    const int fr = lane & 15;
    const int fk = (lane >> 4) * 8;

    f32x4 acc[8];
#pragma unroll
    for (int t = 0; t < 8; ++t) acc[t] = (f32x4){0.f, 0.f, 0.f, 0.f};

    const int nsteps = K >> 5;
    for (int s = 0; s < nsteps; ++s) {
        const int k0 = s * 32;
        __syncthreads();
        // ---- stage A (f32 -> hi/lo bf16) ----
        const float* Ab; int kof; float sc;
        if (K == 256 && k0 >= 128) { Ab = A1; kof = k0 - 128; sc = scA1; }
        else                       { Ab = A0; kof = k0;       sc = 1.0f; }
#pragma unroll
        for (int ch = 0; ch < 32; ch += 16) {
            float4 v = *reinterpret_cast<const float4*>(
                Ab + (size_t)sa_ng * HD + kof + ch + sa_k4);
            float vv[4] = {v.x * sc, v.y * sc, v.z * sc, v.w * sc};
            ushort4 hi, lo;
            hi.x = f2bf(vv[0]); lo.x = f2bf(vv[0] - bf2f(hi.x));
            hi.y = f2bf(vv[1]); lo.y = f2bf(vv[1] - bf2f(hi.y));
            hi.z = f2bf(vv[2]); lo.z = f2bf(vv[2] - bf2f(hi.z));
            hi.w = f2bf(vv[3]); lo.w = f2bf(vv[3] - bf2f(hi.w));
            *reinterpret_cast<ushort4*>(&Ahi_s[sa_row][ch + sa_k4]) = hi;
            *reinterpret_cast<ushort4*>(&Alo_s[sa_row][ch + sa_k4]) = lo;
        }
        // ---- stage B (straight copy of pre-converted transposed W) ----
        {
            const ushort* ph = WT_hi + (size_t)sb_c * wstride + kw0 + k0 + sb_h;
            const ushort* pl = WT_lo + (size_t)sb_c * wstride + kw0 + k0 + sb_h;
            *reinterpret_cast<uint4*>(&Bhi_s[sb_c][sb_h])     = *reinterpret_cast<const uint4*>(ph);
            *reinterpret_cast<uint4*>(&Bhi_s[sb_c][sb_h + 8]) = *reinterpret_cast<const uint4*>(ph + 8);
            *reinterpret_cast<uint4*>(&Blo_s[sb_c][sb_h])     = *reinterpret_cast<const uint4*>(pl);
            *reinterpret_cast<uint4*>(&Blo_s[sb_c][sb_h + 8]) = *reinterpret_cast<const uint4*>(pl + 8);
        }
        __syncthreads();
        // ---- MFMA: 8 col-tiles x 3 products ----
        bf16x8 ah = *reinterpret_cast<bf16x8*>(&Ahi_s[wv * 16 + fr][fk]);
        bf16x8 al = *reinterpret_cast<bf16x8*>(&Alo_s[wv * 16 + fr][fk]);
#pragma unroll
        for (int t = 0; t < 8; ++t) {
            bf16x8 bh = *reinterpret_cast<bf16x8*>(&Bhi_s[t * 16 + fr][fk]);
            bf16x8 bl = *reinterpret_cast<bf16x8*>(&Blo_s[t * 16 + fr][fk]);
            acc[t] = __builtin_amdgcn_mfma_f32_16x16x32_bf16(ah, bh, acc[t], 0, 0, 0);
            acc[t] = __builtin_amdgcn_mfma_f32_16x16x32_bf16(al, bh, acc[t], 0, 0, 0);
            acc[t] = __builtin_amdgcn_mfma_f32_16x16x32_bf16(ah, bl, acc[t], 0, 0, 0);
        }
    }
    // ---- epilogue: C/D map col=lane&15, row=(lane>>4)*4+reg ----
#pragma unroll
    for (int reg = 0; reg < 4; ++reg) {
        int n = n_base + wv * 16 + (lane >> 4) * 4 + reg;
        if (n < N) {
            float bs = bscale ? bscale[n] : 1.0f;
#pragma unroll
            for (int t = 0; t < 8; ++t) {
                int c = t * 16 + fr;
                float v = acc[t][reg] + (bias ? bias[c] * bs : 0.0f);
                out[(size_t)n * HD + c] = relu ? fmaxf(v, 0.0f) : v;
            }
        }
    }
}

// ---------------- node head: relu(h@Wn1+bn1)@Wn2+bn2 ----------------
__global__ __launch_bounds__(256) void node_head_kernel(
    const float* __restrict__ h,
    const float* __restrict__ W1, const float* __restrict__ b1,
    const float* __restrict__ W2, const float* __restrict__ b2,
    float* __restrict__ out, int N)
{
    int n = blockIdx.x * 4 + (threadIdx.x >> 6);
    int lane = threadIdx.x & 63;
    if (n >= N) return;
    const float* hr = h + (size_t)n * HD;
    float t = b1[lane];
#pragma unroll 16
    for (int k = 0; k < HD; ++k)
        t = fmaf(hr[k], W1[k * 64 + lane], t);
    t = fmaxf(t, 0.0f);
    float o0 = t * W2[lane * 2 + 0];
    float o1 = t * W2[lane * 2 + 1];
#pragma unroll
    for (int sft = 32; sft > 0; sft >>= 1) {
        o0 += __shfl_xor(o0, sft);
        o1 += __shfl_xor(o1, sft);
    }
    if (lane == 0) {
        out[(size_t)n * 2 + 0] = o0 + b2[0];
        out[(size_t)n * 2 + 1] = o1 + b2[1];
    }
}

// ---------------- fused edge head, CSR-ordered, all-register t1 ----------------
// Wave wv owns edges [wv*16, wv*16+16). Lane (fr, hi): computes t1 cols
// {kt*32 + hi*8 .. +8} for edge fr in registers (split bf16 hi/lo = MFMA A frags),
// then t2 = relu(t1@W2+b2) via MFMA (B frags from L2), then t2@W3+b3 in-register.
__global__ __launch_bounds__(256) void edge_head_kernel(
    const float* __restrict__ P, const float* __restrict__ Q,
    const int* __restrict__ csr_src, const int* __restrict__ csr_dst,
    const int* __restrict__ csr_eid,
    const float* __restrict__ ea,
    const float* __restrict__ W1c, const float* __restrict__ b1,
    const ushort* __restrict__ W2Th, const ushort* __restrict__ W2Tl,  // [64][128]
    const float* __restrict__ b2,
    const float* __restrict__ W3, const float* __restrict__ b3,
    float* __restrict__ out, int E)
{
    const int tid  = threadIdx.x;
    const int base = blockIdx.x * 64;
    const int lane = tid & 63, wv = tid >> 6;
    const int fr = lane & 15;          // edge within wave-tile / output col idx
    const int hi16 = lane >> 4;        // 0..3
    const int fk = hi16 * 8;           // k-offset within 32-chunk

    // ---- phase 1: build this lane's A-fragments in registers ----
    const int slot = min(base + wv * 16 + fr, E - 1);
    const int sn  = csr_src[slot];
    const int dn  = csr_dst[slot];
    const int eid = csr_eid[slot];

    float eav[8];
    {
        float4 e0 = *reinterpret_cast<const float4*>(ea + (size_t)eid * 8);
        float4 e1 = *reinterpret_cast<const float4*>(ea + (size_t)eid * 8 + 4);
        eav[0] = e0.x; eav[1] = e0.y; eav[2] = e0.z; eav[3] = e0.w;
        eav[4] = e1.x; eav[5] = e1.y; eav[6] = e1.z; eav[7] = e1.w;
    }

    bf16x8 ah[4], al[4];
#pragma unroll
    for (int kt = 0; kt < 4; ++kt) {
        const int c0 = kt * 32 + fk;
        float4 p0 = *reinterpret_cast<const float4*>(P + (size_t)sn * HD + c0);
        float4 p1 = *reinterpret_cast<const float4*>(P + (size_t)sn * HD + c0 + 4);
        float4 q0 = *reinterpret_cast<const float4*>(Q + (size_t)dn * HD + c0);
        float4 q1 = *reinterpret_cast<const float4*>(Q + (size_t)dn * HD + c0 + 4);
        float4 b0 = *reinterpret_cast<const float4*>(b1 + c0);
        float4 b1v = *reinterpret_cast<const float4*>(b1 + c0 + 4);
        float v[8];
        v[0] = p0.x + q0.x + b0.x;  v[1] = p0.y + q0.y + b0.y;
        v[2] = p0.z + q0.z + b0.z;  v[3] = p0.w + q0.w + b0.w;
        v[4] = p1.x + q1.x + b1v.x; v[5] = p1.y + q1.y + b1v.y;
        v[6] = p1.z + q1.z + b1v.z; v[7] = p1.w + q1.w + b1v.w;
#pragma unroll
        for (int k = 0; k < 8; ++k) {
            float4 w0 = *reinterpret_cast<const float4*>(W1c + k * HD + c0);
            float4 w1 = *reinterpret_cast<const float4*>(W1c + k * HD + c0 + 4);
            v[0] = fmaf(eav[k], w0.x, v[0]); v[1] = fmaf(eav[k], w0.y, v[1]);
            v[2] = fmaf(eav[k], w0.z, v[2]); v[3] = fmaf(eav[k], w0.w, v[3]);
            v[4] = fmaf(eav[k], w1.x, v[4]); v[5] = fmaf(eav[k], w1.y, v[5]);
            v[6] = fmaf(eav[k], w1.z, v[6]); v[7] = fmaf(eav[k], w1.w, v[7]);
        }
#pragma unroll
        for (int j = 0; j < 8; ++j) {
            float t = fmaxf(v[j], 0.0f);
            ushort h = f2bf(t);
            ushort l = f2bf(t - bf2f(h));
            ah[kt][j] = (short)h;
            al[kt][j] = (short)l;
        }
    }

    // ---- phase 2: t2 = t1 @ W2 via MFMA (B frags from L2) ----
    f32x4 acc[4];
#pragma unroll
    for (int t = 0; t < 4; ++t) acc[t] = (f32x4){0.f, 0.f, 0.f, 0.f};
#pragma unroll
    for (int kt = 0; kt < 4; ++kt) {
#pragma unroll
        for (int t = 0; t < 4; ++t) {
            const size_t boff = (size_t)(t * 16 + fr) * 128 + kt * 32 + fk;
            bf16x8 bh = *reinterpret_cast<const bf16x8*>(W2Th + boff);
            bf16x8 bl = *reinterpret_cast<const bf16x8*>(W2Tl + boff);
            acc[t] = __builtin_amdgcn_mfma_f32_16x16x32_bf16(ah[kt], bh, acc[t], 0, 0, 0);
            acc[t] = __builtin_amdgcn_mfma_f32_16x16x32_bf16(al[kt], bh, acc[t], 0, 0, 0);
            acc[t] = __builtin_amdgcn_mfma_f32_16x16x32_bf16(ah[kt], bl, acc[t], 0, 0, 0);
        }
    }

    // ---- phase 3: out = relu(t2+b2) @ W3 + b3, in registers ----
    // C/D map: col = t*16+fr, edge-row = wv*16 + (lane>>4)*4 + reg.
    float b2v[4];
#pragma unroll
    for (int t = 0; t < 4; ++t) b2v[t] = b2[t * 16 + fr];
#pragma unroll
    for (int reg = 0; reg < 4; ++reg) {
        int erow = wv * 16 + hi16 * 4 + reg;
        float p[6];
#pragma unroll
        for (int j = 0; j < 6; ++j) p[j] = 0.0f;
#pragma unroll
        for (int t = 0; t < 4; ++t) {
            int c = t * 16 + fr;
            float t2v = fmaxf(acc[t][reg] + b2v[t], 0.0f);
#pragma unroll
            for (int j = 0; j < 6; ++j)
                p[j] = fmaf(t2v, W3[c * 6 + j], p[j]);
        }
#pragma unroll
        for (int j = 0; j < 6; ++j) {
#pragma unroll
            for (int sft = 1; sft < 16; sft <<= 1)
                p[j] += __shfl_xor(p[j], sft);
        }
        int oslot = base + erow;
        if (fr < 6 && oslot < E) {
            int oeid = csr_eid[oslot];
            out[(size_t)oeid * 6 + fr] = p[fr] + b3[fr];
        }
    }
}

// ---------------- launch ----------------
extern "C" void kernel_launch(void* const* d_in, const int* in_sizes, int n_in,
                              void* d_out, int out_size, void* d_ws, size_t ws_size,
                              hipStream_t stream)
{
    (void)n_in; (void)out_size; (void)ws_size;
    const float* x     = (const float*)d_in[0];
    const int*   ei    = (const int*)d_in[1];
    const float* eattr = (const float*)d_in[2];
    const float* Wenc = (const float*)d_in[4];
    const float* benc = (const float*)d_in[5];
    const float* Wmsg = (const float*)d_in[6];
    const float* bmsg = (const float*)d_in[7];
    const float* Wupd = (const float*)d_in[8];
    const float* bupd = (const float*)d_in[9];
    const float* Wn1  = (const float*)d_in[10];
    const float* bn1  = (const float*)d_in[11];
    const float* Wn2  = (const float*)d_in[12];
    const float* bn2  = (const float*)d_in[13];
    const float* We1  = (const float*)d_in[14];
    const float* be1  = (const float*)d_in[15];
    const float* We2  = (const float*)d_in[16];
    const float* be2  = (const float*)d_in[17];
    const float* We3  = (const float*)d_in[18];
    const float* be3  = (const float*)d_in[19];

    const int N = in_sizes[0] / 16;
    const int E = in_sizes[1] / 2;
    const int* src = ei;
    const int* dst = ei + E;

    float* h0   = (float*)d_ws;
    float* h1   = h0 + (size_t)N * HD;
    float* S    = h1 + (size_t)N * HD;     // pull target; later reused as P
    float* agg  = S  + (size_t)N * HD;     // agg; later reused as Q
    float* rs   = agg + (size_t)N * HD;
    float* ss   = rs + N;
    int* deg_i  = (int*)(ss + N);
    int* off    = deg_i + N;               // N+1
    int* cursor = off + N + 1;
    int* csr_s  = cursor + N;              // E
    int* csr_d  = csr_s + E;               // E
    int* csr_e  = csr_d + E;               // E
    ushort* wt  = (ushort*)(((uintptr_t)(csr_e + E) + 255) & ~(uintptr_t)255);
    ushort* wtm_hi = wt;                   // 128*256 each
    ushort* wtm_lo = wtm_hi + 32768;
    ushort* wtu_hi = wtm_lo + 32768;
    ushort* wtu_lo = wtu_hi + 32768;
    ushort* wte_hi = wtu_lo + 32768;
    ushort* wte_lo = wte_hi + 32768;
    ushort* w2t_hi = wte_lo + 32768;       // 64*128 each
    ushort* w2t_lo = w2t_hi + 8192;

    float* node_out = (float*)d_out;
    float* edge_out = node_out + (size_t)N * 2;

    // ---- CSR build ----
    hipMemsetAsync(deg_i, 0, (size_t)N * sizeof(int), stream);
    hipMemsetAsync(cursor, 0, (size_t)N * sizeof(int), stream);
    deg_int_kernel<<<(E + 255) / 256, 256, 0, stream>>>(dst, deg_i, E);
    scan_kernel<<<1, 256, 0, stream>>>(deg_i, off, N);
    degscale_kernel<<<(N + 255) / 256, 256, 0, stream>>>(deg_i, rs, ss, N);
    csr_fill_kernel<<<(E + 255) / 256, 256, 0, stream>>>(
        src, dst, off, cursor, csr_s, csr_d, csr_e, E);

    // ---- weight prep: transposed bf16 hi/lo ----
    wt_convert_kernel<<<128, 256, 0, stream>>>(Wmsg, wtm_hi, wtm_lo, 256, 128);
    wt_convert_kernel<<<128, 256, 0, stream>>>(Wupd, wtu_hi, wtu_lo, 256, 128);
    wt_convert_kernel<<<128, 256, 0, stream>>>(We1,  wte_hi, wte_lo, 256, 128);
    wt_convert_kernel<<<32,  256, 0, stream>>>(We2,  w2t_hi, w2t_lo, 128, 64);

    // ---- encoder ----
    encoder_kernel<<<(N + 1) / 2, 256, 0, stream>>>(x, Wenc, benc, h0, N);

    // ---- GNN layers ----
    const int gblocks = (N + 63) / 64;
    float* hc = h0;
    float* hn = h1;
    for (int l = 0; l < 3; ++l) {
        pull_kernel<<<(N + 3) / 4, 256, 0, stream>>>(hc, off, csr_s, rs, S, N);
        gemm_mfma_kernel<<<gblocks, 256, 0, stream>>>(
            S, hc, ss, wtm_hi, wtm_lo, 256, 0, bmsg, ss, agg, N, 256, 0);
        gemm_mfma_kernel<<<gblocks, 256, 0, stream>>>(
            hc, agg, nullptr, wtu_hi, wtu_lo, 256, 0, bupd, nullptr, hn, N, 256, 1);
        float* t = hc; hc = hn; hn = t;
    }

    // ---- P/Q precompute for edge head ----
    float* Pb = S;
    float* Qb = agg;
    gemm_mfma_kernel<<<gblocks, 256, 0, stream>>>(
        hc, nullptr, nullptr, wte_hi, wte_lo, 256, 0, nullptr, nullptr, Pb, N, 128, 0);
    gemm_mfma_kernel<<<gblocks, 256, 0, stream>>>(
        hc, nullptr, nullptr, wte_hi, wte_lo, 256, 128, nullptr, nullptr, Qb, N, 128, 0);

    // ---- heads ----
    node_head_kernel<<<(N + 3) / 4, 256, 0, stream>>>(
        hc, Wn1, bn1, Wn2, bn2, node_out, N);
    edge_head_kernel<<<(E + 63) / 64, 256, 0, stream>>>(
        Pb, Qb, csr_s, csr_d, csr_e, eattr, We1 + (size_t)256 * HD, be1,
        w2t_hi, w2t_lo, be2, We3, be3, edge_out, E);
}

// Round 9
// 942.839 us; speedup vs baseline: 1.2945x; 1.0362x over previous
//
#include <hip/hip_runtime.h>
#include <hip/hip_bf16.h>

#define HD 128   // hidden size

typedef __attribute__((ext_vector_type(8))) short bf16x8;
typedef __attribute__((ext_vector_type(4))) float f32x4;

__device__ __forceinline__ ushort f2bf(float f) {
    uint u = __float_as_uint(f);
    return (ushort)((u + 0x7FFFu + ((u >> 16) & 1u)) >> 16);
}
__device__ __forceinline__ float bf2f(ushort h) {
    return __uint_as_float(((uint)h) << 16);
}

// ---------------- encoder: h = x @ W_enc + b_enc ----------------
__global__ __launch_bounds__(256) void encoder_kernel(
    const float* __restrict__ x, const float* __restrict__ W,
    const float* __restrict__ b, float* __restrict__ h, int N)
{
    int n = blockIdx.x * 2 + (threadIdx.x >> 7);
    int c = threadIdx.x & 127;
    if (n >= N) return;
    const float* xr = x + (size_t)n * 16;
    float acc = b[c];
#pragma unroll
    for (int k = 0; k < 16; ++k)
        acc = fmaf(xr[k], W[k * HD + c], acc);
    h[(size_t)n * HD + c] = acc;
}

// ---------------- int degree histogram ----------------
__global__ __launch_bounds__(256) void deg_int_kernel(
    const int* __restrict__ dst, int* __restrict__ deg, int E)
{
    int e = blockIdx.x * 256 + threadIdx.x;
    if (e < E) atomicAdd(&deg[dst[e]], 1);
}

// r = 1/max(cnt,1), s = cnt/max(cnt,1)
__global__ __launch_bounds__(256) void degscale_kernel(
    const int* __restrict__ deg, float* __restrict__ r,
    float* __restrict__ s, int N)
{
    int n = blockIdx.x * 256 + threadIdx.x;
    if (n < N) {
        float c = (float)deg[n];
        float cp = fmaxf(c, 1.0f);
        r[n] = 1.0f / cp;
        s[n] = c / cp;
    }
}

// ---------------- single-block exclusive scan ----------------
__global__ __launch_bounds__(256) void scan_kernel(
    const int* __restrict__ deg, int* __restrict__ off, int N)
{
    __shared__ int wsum[4];
    const int tid = threadIdx.x;
    const int lane = tid & 63;
    const int wid = tid >> 6;
    int carry = 0;
    for (int base = 0; base < N; base += 256) {
        int i = base + tid;
        int v = (i < N) ? deg[i] : 0;
        int x = v;
#pragma unroll
        for (int d = 1; d < 64; d <<= 1) {
            int y = __shfl_up(x, d);
            if (lane >= d) x += y;
        }
        if (lane == 63) wsum[wid] = x;
        __syncthreads();
        int add = 0;
#pragma unroll
        for (int w = 0; w < 3; ++w)
            if (w < wid) add += wsum[w];
        if (i < N) off[i] = carry + add + x - v;
        carry += wsum[0] + wsum[1] + wsum[2] + wsum[3];
        __syncthreads();
    }
    if (tid == 0) off[N] = carry;
}

// ---------------- CSR fill: slot -> (src, dst, eid) ----------------
__global__ __launch_bounds__(256) void csr_fill_kernel(
    const int* __restrict__ src, const int* __restrict__ dst,
    const int* __restrict__ off, int* __restrict__ cursor,
    int* __restrict__ csr_src, int* __restrict__ csr_dst,
    int* __restrict__ csr_eid, int E)
{
    int e = blockIdx.x * 256 + threadIdx.x;
    if (e < E) {
        int d = dst[e];
        int p = atomicAdd(&cursor[d], 1);
        int pos = off[d] + p;
        csr_src[pos] = src[e];
        csr_dst[pos] = d;
        csr_eid[pos] = e;
    }
}

// ---------------- pull aggregation: S[n] = r[n] * sum h[src_e] ----------------
__global__ __launch_bounds__(256) void pull_kernel(
    const float* __restrict__ h, const int* __restrict__ off,
    const int* __restrict__ csr, const float* __restrict__ r,
    float* __restrict__ S, int N)
{
    int n = blockIdx.x * 4 + (threadIdx.x >> 6);
    if (n >= N) return;
    int lane = threadIdx.x & 63;
    int beg = off[n], end = off[n + 1];
    float ax = 0.0f, ay = 0.0f;
    for (int i = beg; i < end; ++i) {
        int s = csr[i];
        float2 v = *reinterpret_cast<const float2*>(h + (size_t)s * HD + 2 * lane);
        ax += v.x; ay += v.y;
    }
    float rr = r[n];
    *reinterpret_cast<float2*>(S + (size_t)n * HD + 2 * lane) =
        make_float2(ax * rr, ay * rr);
}

// ---------------- M12 = [Wm_top@Wu_bot ; Wm_bot@Wu_bot] (f32 exact) ----------------
__global__ __launch_bounds__(128) void mm2_kernel(
    const float* __restrict__ Wmsg, const float* __restrict__ Wupd,
    float* __restrict__ M)
{
    int b = blockIdx.x;              // 0..255
    int j = threadIdx.x;             // 0..127
    const float* Ar = Wmsg + (size_t)b * 128;     // rows 0..255 of Wmsg
    const float* B  = Wupd + 128 * 128;           // Wu_bot
    float acc = 0.0f;
#pragma unroll 8
    for (int k = 0; k < 128; ++k)
        acc = fmaf(Ar[k], B[k * 128 + j], acc);
    M[(size_t)b * 128 + j] = acc;
}

// cvec = bmsg @ Wu_bot
__global__ __launch_bounds__(128) void cvec_kernel(
    const float* __restrict__ bmsg, const float* __restrict__ Wupd,
    float* __restrict__ cvec)
{
    int j = threadIdx.x;
    const float* B = Wupd + 128 * 128;
    float acc = 0.0f;
#pragma unroll 8
    for (int k = 0; k < 128; ++k)
        acc = fmaf(bmsg[k], B[k * 128 + j], acc);
    cvec[j] = acc;
}

// ---------------- build fused W'T [c][384] bf16 hi/lo ----------------
// k<128: Wu_top row k; k in [128,384): M12 row k-128
__global__ __launch_bounds__(256) void wft_build_kernel(
    const float* __restrict__ Wupd, const float* __restrict__ M12,
    ushort* __restrict__ WThi, ushort* __restrict__ WTlo)
{
    int idx = blockIdx.x * 256 + threadIdx.x;
    if (idx >= 384 * 128) return;
    int k = idx >> 7, c = idx & 127;
    float a = (k < 128) ? Wupd[idx] : M12[(size_t)(k - 128) * 128 + c];
    ushort hi = f2bf(a);
    ushort lo = f2bf(a - bf2f(hi));
    WThi[(size_t)c * 384 + k] = hi;
    WTlo[(size_t)c * 384 + k] = lo;
}

// ---------------- W[K][C] -> transposed bf16 hi/lo: WT[c][k] ----------------
__global__ __launch_bounds__(256) void wt_convert_kernel(
    const float* __restrict__ W, ushort* __restrict__ WThi,
    ushort* __restrict__ WTlo, int K, int C)
{
    int idx = blockIdx.x * 256 + threadIdx.x;
    if (idx >= K * C) return;
    int k = idx / C, c = idx % C;
    float a = W[idx];
    ushort hi = f2bf(a);
    ushort lo = f2bf(a - bf2f(hi));
    WThi[c * K + k] = hi;
    WTlo[c * K + k] = lo;
}

// ---------------- fused layer GEMM: h' = relu([h|S|s*h] @ W' + b_upd + s*cvec) ----------------
// K=384. A,B LDS-staged (r4-proven structure).
__global__ __launch_bounds__(256) void gemm_fused_kernel(
    const float* __restrict__ h, const float* __restrict__ S,
    const float* __restrict__ ss,
    const ushort* __restrict__ WT_hi, const ushort* __restrict__ WT_lo,
    const float* __restrict__ bupd, const float* __restrict__ cvec,
    float* __restrict__ out, int N)
{
    __shared__ __align__(16) ushort Ahi_s[64][40];
    __shared__ __align__(16) ushort Alo_s[64][40];
    __shared__ __align__(16) ushort Bhi_s[128][40];
    __shared__ __align__(16) ushort Blo_s[128][40];

    const int tid    = threadIdx.x;
    const int n_base = blockIdx.x * 64;
    const int sa_row = tid >> 2;
    const int sa_k4  = (tid & 3) * 4;
    const int sa_ng  = min(n_base + sa_row, N - 1);
    const float scA  = ss[sa_ng];
    const int sb_c = tid & 127;
    const int sb_h = (tid >> 7) * 16;
    const int lane = tid & 63, wv = tid >> 6;
    const int fr = lane & 15;
    const int fk = (lane >> 4) * 8;

    f32x4 acc[8];
#pragma unroll
    for (int t = 0; t < 8; ++t) acc[t] = (f32x4){0.f, 0.f, 0.f, 0.f};

    for (int s = 0; s < 12; ++s) {
        const int k0 = s * 32;
        __syncthreads();
        const int part = k0 >> 7;            // 0: h, 1: S, 2: s*h
        const int kof  = k0 & 127;
        const float* Ab = (part == 1) ? S : h;
        const float  sc = (part == 2) ? scA : 1.0f;
#pragma unroll
        for (int ch = 0; ch < 32; ch += 16) {
            float4 v = *reinterpret_cast<const float4*>(
                Ab + (size_t)sa_ng * HD + kof + ch + sa_k4);
            float vv[4] = {v.x * sc, v.y * sc, v.z * sc, v.w * sc};
            ushort4 hi, lo;
            hi.x = f2bf(vv[0]); lo.x = f2bf(vv[0] - bf2f(hi.x));
            hi.y = f2bf(vv[1]); lo.y = f2bf(vv[1] - bf2f(hi.y));
            hi.z = f2bf(vv[2]); lo.z = f2bf(vv[2] - bf2f(hi.z));
            hi.w = f2bf(vv[3]); lo.w = f2bf(vv[3] - bf2f(hi.w));
            *reinterpret_cast<ushort4*>(&Ahi_s[sa_row][ch + sa_k4]) = hi;
            *reinterpret_cast<ushort4*>(&Alo_s[sa_row][ch + sa_k4]) = lo;
        }
        {
            const ushort* ph = WT_hi + (size_t)sb_c * 384 + k0 + sb_h;
            const ushort* pl = WT_lo + (size_t)sb_c * 384 + k0 + sb_h;
            *reinterpret_cast<uint4*>(&Bhi_s[sb_c][sb_h])     = *reinterpret_cast<const uint4*>(ph);
            *reinterpret_cast<uint4*>(&Bhi_s[sb_c][sb_h + 8]) = *reinterpret_cast<const uint4*>(ph + 8);
            *reinterpret_cast<uint4*>(&Blo_s[sb_c][sb_h])     = *reinterpret_cast<const uint4*>(pl);
            *reinterpret_cast<uint4*>(&Blo_s[sb_c][sb_h + 8]) = *reinterpret_cast<const uint4*>(pl + 8);
        }
        __syncthreads();
        bf16x8 ah = *reinterpret_cast<bf16x8*>(&Ahi_s[wv * 16 + fr][fk]);
        bf16x8 al = *reinterpret_cast<bf16x8*>(&Alo_s[wv * 16 + fr][fk]);
#pragma unroll
        for (int t = 0; t < 8; ++t) {
            bf16x8 bh = *reinterpret_cast<bf16x8*>(&Bhi_s[t * 16 + fr][fk]);
            bf16x8 bl = *reinterpret_cast<bf16x8*>(&Blo_s[t * 16 + fr][fk]);
            acc[t] = __builtin_amdgcn_mfma_f32_16x16x32_bf16(ah, bh, acc[t], 0, 0, 0);
            acc[t] = __builtin_amdgcn_mfma_f32_16x16x32_bf16(al, bh, acc[t], 0, 0, 0);
            acc[t] = __builtin_amdgcn_mfma_f32_16x16x32_bf16(ah, bl, acc[t], 0, 0, 0);
        }
    }
#pragma unroll
    for (int reg = 0; reg < 4; ++reg) {
        int n = n_base + wv * 16 + (lane >> 4) * 4 + reg;
        if (n < N) {
            float sv = ss[n];
#pragma unroll
            for (int t = 0; t < 8; ++t) {
                int c = t * 16 + fr;
                float v = acc[t][reg] + bupd[c] + sv * cvec[c];
                out[(size_t)n * HD + c] = fmaxf(v, 0.0f);
            }
        }
    }
}

// ---------------- split-bf16 MFMA GEMM (r4-proven; used for P/Q, K=128) ----------------
__global__ __launch_bounds__(256) void gemm_mfma_kernel(
    const float* __restrict__ A0, const float* __restrict__ A1,
    const float* __restrict__ s1,
    const ushort* __restrict__ WT_hi, const ushort* __restrict__ WT_lo,
    int wstride, int kw0,
    const float* __restrict__ bias, const float* __restrict__ bscale,
    float* __restrict__ out, int N, int K, int relu)
{
    __shared__ __align__(16) ushort Ahi_s[64][40];
    __shared__ __align__(16) ushort Alo_s[64][40];
    __shared__ __align__(16) ushort Bhi_s[128][40];
    __shared__ __align__(16) ushort Blo_s[128][40];

    const int tid    = threadIdx.x;
    const int n_base = blockIdx.x * 64;
    const int sa_row = tid >> 2;
    const int sa_k4  = (tid & 3) * 4;
    const int sa_ng  = min(n_base + sa_row, N - 1);
    const float scA1 = s1 ? s1[sa_ng] : 1.0f;
    const int sb_c = tid & 127;
    const int sb_h = (tid >> 7) * 16;
    const int lane = tid & 63, wv = tid >> 6;
    const int fr = lane & 15;
    const int fk = (lane >> 4) * 8;

    f32x4 acc[8];
#pragma unroll
    for (int t = 0; t < 8; ++t) acc[t] = (f32x4){0.f, 0.f, 0.f, 0.f};

    const int nsteps = K >> 5;
    for (int s = 0; s < nsteps; ++s) {
        const int k0 = s * 32;
        __syncthreads();
        const float* Ab; int kof; float sc;
        if (K == 256 && k0 >= 128) { Ab = A1; kof = k0 - 128; sc = scA1; }
        else                       { Ab = A0; kof = k0;       sc = 1.0f; }
#pragma unroll
        for (int ch = 0; ch < 32; ch += 16) {
            float4 v = *reinterpret_cast<const float4*>(
                Ab + (size_t)sa_ng * HD + kof + ch + sa_k4);
            float vv[4] = {v.x * sc, v.y * sc, v.z * sc, v.w * sc};
            ushort4 hi, lo;
            hi.x = f2bf(vv[0]); lo.x = f2bf(vv[0] - bf2f(hi.x));
            hi.y = f2bf(vv[1]); lo.y = f2bf(vv[1] - bf2f(hi.y));
            hi.z = f2bf(vv[2]); lo.z = f2bf(vv[2] - bf2f(hi.z));
            hi.w = f2bf(vv[3]); lo.w = f2bf(vv[3] - bf2f(hi.w));
            *reinterpret_cast<ushort4*>(&Ahi_s[sa_row][ch + sa_k4]) = hi;
            *reinterpret_cast<ushort4*>(&Alo_s[sa_row][ch + sa_k4]) = lo;
        }
        {
            const ushort* ph = WT_hi + (size_t)sb_c * wstride + kw0 + k0 + sb_h;
            const ushort* pl = WT_lo + (size_t)sb_c * wstride + kw0 + k0 + sb_h;
            *reinterpret_cast<uint4*>(&Bhi_s[sb_c][sb_h])     = *reinterpret_cast<const uint4*>(ph);
            *reinterpret_cast<uint4*>(&Bhi_s[sb_c][sb_h + 8]) = *reinterpret_cast<const uint4*>(ph + 8);
            *reinterpret_cast<uint4*>(&Blo_s[sb_c][sb_h])     = *reinterpret_cast<const uint4*>(pl);
            *reinterpret_cast<uint4*>(&Blo_s[sb_c][sb_h + 8]) = *reinterpret_cast<const uint4*>(pl + 8);
        }
        __syncthreads();
        bf16x8 ah = *reinterpret_cast<bf16x8*>(&Ahi_s[wv * 16 + fr][fk]);
        bf16x8 al = *reinterpret_cast<bf16x8*>(&Alo_s[wv * 16 + fr][fk]);
#pragma unroll
        for (int t = 0; t < 8; ++t) {
            bf16x8 bh = *reinterpret_cast<bf16x8*>(&Bhi_s[t * 16 + fr][fk]);
            bf16x8 bl = *reinterpret_cast<bf16x8*>(&Blo_s[t * 16 + fr][fk]);
            acc[t] = __builtin_amdgcn_mfma_f32_16x16x32_bf16(ah, bh, acc[t], 0, 0, 0);
            acc[t] = __builtin_amdgcn_mfma_f32_16x16x32_bf16(al, bh, acc[t], 0, 0, 0);
            acc[t] = __builtin_amdgcn_mfma_f32_16x16x32_bf16(ah, bl, acc[t], 0, 0, 0);
        }
    }
#pragma unroll
    for (int reg = 0; reg < 4; ++reg) {
        int n = n_base + wv * 16 + (lane >> 4) * 4 + reg;
        if (n < N) {
            float bs = bscale ? bscale[n] : 1.0f;
#pragma unroll
            for (int t = 0; t < 8; ++t) {
                int c = t * 16 + fr;
                float v = acc[t][reg] + (bias ? bias[c] * bs : 0.0f);
                out[(size_t)n * HD + c] = relu ? fmaxf(v, 0.0f) : v;
            }
        }
    }
}

// ---------------- node head ----------------
__global__ __launch_bounds__(256) void node_head_kernel(
    const float* __restrict__ h,
    const float* __restrict__ W1, const float* __restrict__ b1,
    const float* __restrict__ W2, const float* __restrict__ b2,
    float* __restrict__ out, int N)
{
    int n = blockIdx.x * 4 + (threadIdx.x >> 6);
    int lane = threadIdx.x & 63;
    if (n >= N) return;
    const float* hr = h + (size_t)n * HD;
    float t = b1[lane];
#pragma unroll 16
    for (int k = 0; k < HD; ++k)
        t = fmaf(hr[k], W1[k * 64 + lane], t);
    t = fmaxf(t, 0.0f);
    float o0 = t * W2[lane * 2 + 0];
    float o1 = t * W2[lane * 2 + 1];
#pragma unroll
    for (int sft = 32; sft > 0; sft >>= 1) {
        o0 += __shfl_xor(o0, sft);
        o1 += __shfl_xor(o1, sft);
    }
    if (lane == 0) {
        out[(size_t)n * 2 + 0] = o0 + b2[0];
        out[(size_t)n * 2 + 1] = o1 + b2[1];
    }
}

// ---------------- fused edge head: coalesced LDS staging + MFMA ----------------
__global__ __launch_bounds__(256) void edge_head_kernel(
    const float* __restrict__ P, const float* __restrict__ Q,
    const int* __restrict__ csr_src, const int* __restrict__ csr_dst,
    const int* __restrict__ csr_eid,
    const float* __restrict__ ea,
    const float* __restrict__ W1c, const float* __restrict__ b1,
    const ushort* __restrict__ W2Th, const ushort* __restrict__ W2Tl,  // [64][128]
    const float* __restrict__ b2,
    const float* __restrict__ W3, const float* __restrict__ b3,
    float* __restrict__ out, int E)
{
    __shared__ float t1pre[64][132];
    __shared__ float ea_s[64][8];
    __shared__ int sn_s[64], dn_s[64], eid_s[64];

    const int tid  = threadIdx.x;
    const int base = blockIdx.x * 64;
    const int lane = tid & 63, wv = tid >> 6;

    if (tid < 64) {
        int slot = min(base + tid, E - 1);
        sn_s[tid]  = csr_src[slot];
        dn_s[tid]  = csr_dst[slot];
        eid_s[tid] = csr_eid[slot];
    }
    __syncthreads();

    // ---- ea staging (uses eid_s) ----
    if (tid < 128) {
        int e = tid >> 1, q = (tid & 1) * 4;
        float4 v = *reinterpret_cast<const float4*>(ea + (size_t)eid_s[e] * 8 + q);
        *reinterpret_cast<float4*>(&ea_s[e][q]) = v;
    }

    // ---- coalesced row staging: wave wv stages edges [wv*16, wv*16+16) ----
    float2 b1v = *reinterpret_cast<const float2*>(b1 + 2 * lane);
    float2 pv[16], qv[16];
#pragma unroll
    for (int i = 0; i < 16; ++i) {
        int e = wv * 16 + i;
        pv[i] = *reinterpret_cast<const float2*>(P + (size_t)sn_s[e] * HD + 2 * lane);
    }
#pragma unroll
    for (int i = 0; i < 16; ++i) {
        int e = wv * 16 + i;
        qv[i] = *reinterpret_cast<const float2*>(Q + (size_t)dn_s[e] * HD + 2 * lane);
    }
#pragma unroll
    for (int i = 0; i < 16; ++i) {
        int e = wv * 16 + i;
        t1pre[e][2 * lane]     = pv[i].x + qv[i].x + b1v.x;
        t1pre[e][2 * lane + 1] = pv[i].y + qv[i].y + b1v.y;
    }
    __syncthreads();

    // ---- fragment phase: t1 = relu(t1pre + ea@W1c) -> split-bf16 A frags ----
    const int fr = lane & 15, hi16 = lane >> 4, fk = hi16 * 8;
    const int eL = wv * 16 + fr;
    float eav[8];
#pragma unroll
    for (int k = 0; k < 8; ++k) eav[k] = ea_s[eL][k];

    bf16x8 ah[4], al[4];
#pragma unroll
    for (int kt = 0; kt < 4; ++kt) {
        const int c0 = kt * 32 + fk;
        float4 v0 = *reinterpret_cast<float4*>(&t1pre[eL][c0]);
        float4 v1 = *reinterpret_cast<float4*>(&t1pre[eL][c0 + 4]);
        float v[8] = {v0.x, v0.y, v0.z, v0.w, v1.x, v1.y, v1.z, v1.w};
#pragma unroll
        for (int k = 0; k < 8; ++k) {
            float4 w0 = *reinterpret_cast<const float4*>(W1c + k * HD + c0);
            float4 w1 = *reinterpret_cast<const float4*>(W1c + k * HD + c0 + 4);
            v[0] = fmaf(eav[k], w0.x, v[0]); v[1] = fmaf(eav[k], w0.y, v[1]);
            v[2] = fmaf(eav[k], w0.z, v[2]); v[3] = fmaf(eav[k], w0.w, v[3]);
            v[4] = fmaf(eav[k], w1.x, v[4]); v[5] = fmaf(eav[k], w1.y, v[5]);
            v[6] = fmaf(eav[k], w1.z, v[6]); v[7] = fmaf(eav[k], w1.w, v[7]);
        }
#pragma unroll
        for (int j = 0; j < 8; ++j) {
            float t = fmaxf(v[j], 0.0f);
            ushort h = f2bf(t);
            ushort l = f2bf(t - bf2f(h));
            ah[kt][j] = (short)h;
            al[kt][j] = (short)l;
        }
    }

    // ---- phase 2: t2 = t1 @ W2 via MFMA (B frags from L2) ----
    f32x4 acc[4];
#pragma unroll
    for (int t = 0; t < 4; ++t) acc[t] = (f32x4){0.f, 0.f, 0.f, 0.f};
#pragma unroll
    for (int kt = 0; kt < 4; ++kt) {
#pragma unroll
        for (int t = 0; t < 4; ++t) {
            const size_t boff = (size_t)(t * 16 + fr) * 128 + kt * 32 + fk;
            bf16x8 bh = *reinterpret_cast<const bf16x8*>(W2Th + boff);
            bf16x8 bl = *reinterpret_cast<const bf16x8*>(W2Tl + boff);
            acc[t] = __builtin_amdgcn_mfma_f32_16x16x32_bf16(ah[kt], bh, acc[t], 0, 0, 0);
            acc[t] = __builtin_amdgcn_mfma_f32_16x16x32_bf16(al[kt], bh, acc[t], 0, 0, 0);
            acc[t] = __builtin_amdgcn_mfma_f32_16x16x32_bf16(ah[kt], bl, acc[t], 0, 0, 0);
        }
    }

    // ---- phase 3: out = relu(t2+b2) @ W3 + b3, in-register reduce ----
    float b2v[4];
#pragma unroll
    for (int t = 0; t < 4; ++t) b2v[t] = b2[t * 16 + fr];
#pragma unroll
    for (int reg = 0; reg < 4; ++reg) {
        int erow = wv * 16 + hi16 * 4 + reg;
        float p[6];
#pragma unroll
        for (int j = 0; j < 6; ++j) p[j] = 0.0f;
#pragma unroll
        for (int t = 0; t < 4; ++t) {
            int c = t * 16 + fr;
            float t2v = fmaxf(acc[t][reg] + b2v[t], 0.0f);
#pragma unroll
            for (int j = 0; j < 6; ++j)
                p[j] = fmaf(t2v, W3[c * 6 + j], p[j]);
        }
#pragma unroll
        for (int j = 0; j < 6; ++j) {
#pragma unroll
            for (int sft = 1; sft < 16; sft <<= 1)
                p[j] += __shfl_xor(p[j], sft);
        }
        int oslot = base + erow;
        if (fr < 6 && oslot < E) {
            out[(size_t)eid_s[erow] * 6 + fr] = p[fr] + b3[fr];
        }
    }
}

// ---------------- launch ----------------
extern "C" void kernel_launch(void* const* d_in, const int* in_sizes, int n_in,
                              void* d_out, int out_size, void* d_ws, size_t ws_size,
                              hipStream_t stream)
{
    (void)n_in; (void)out_size; (void)ws_size;
    const float* x     = (const float*)d_in[0];
    const int*   ei    = (const int*)d_in[1];
    const float* eattr = (const float*)d_in[2];
    const float* Wenc = (const float*)d_in[4];
    const float* benc = (const float*)d_in[5];
    const float* Wmsg = (const float*)d_in[6];
    const float* bmsg = (const float*)d_in[7];
    const float* Wupd = (const float*)d_in[8];
    const float* bupd = (const float*)d_in[9];
    const float* Wn1  = (const float*)d_in[10];
    const float* bn1  = (const float*)d_in[11];
    const float* Wn2  = (const float*)d_in[12];
    const float* bn2  = (const float*)d_in[13];
    const float* We1  = (const float*)d_in[14];
    const float* be1  = (const float*)d_in[15];
    const float* We2  = (const float*)d_in[16];
    const float* be2  = (const float*)d_in[17];
    const float* We3  = (const float*)d_in[18];
    const float* be3  = (const float*)d_in[19];

    const int N = in_sizes[0] / 16;
    const int E = in_sizes[1] / 2;
    const int* src = ei;
    const int* dst = ei + E;

    float* h0   = (float*)d_ws;
    float* h1   = h0 + (size_t)N * HD;
    float* S    = h1 + (size_t)N * HD;     // pull target; later reused as P
    float* Qb   = S  + (size_t)N * HD;     // later Q
    float* rs   = Qb + (size_t)N * HD;
    float* ss   = rs + N;
    int* deg_i  = (int*)(ss + N);
    int* off    = deg_i + N;               // N+1
    int* cursor = off + N + 1;
    int* csr_s  = cursor + N;              // E
    int* csr_d  = csr_s + E;               // E
    int* csr_e  = csr_d + E;               // E
    float* fM   = (float*)(((uintptr_t)(csr_e + E) + 255) & ~(uintptr_t)255);
    float* M12  = fM;                      // 256*128
    float* cvec = fM + 32768;              // 128
    ushort* wt  = (ushort*)(cvec + 128);
    ushort* wft_hi = wt;                   // 128*384
    ushort* wft_lo = wft_hi + 49152;
    ushort* wte_hi = wft_lo + 49152;       // 128*256
    ushort* wte_lo = wte_hi + 32768;
    ushort* w2t_hi = wte_lo + 32768;       // 64*128
    ushort* w2t_lo = w2t_hi + 8192;

    float* node_out = (float*)d_out;
    float* edge_out = node_out + (size_t)N * 2;

    // ---- CSR build ----
    hipMemsetAsync(deg_i, 0, (size_t)N * sizeof(int), stream);
    hipMemsetAsync(cursor, 0, (size_t)N * sizeof(int), stream);
    deg_int_kernel<<<(E + 255) / 256, 256, 0, stream>>>(dst, deg_i, E);
    scan_kernel<<<1, 256, 0, stream>>>(deg_i, off, N);
    degscale_kernel<<<(N + 255) / 256, 256, 0, stream>>>(deg_i, rs, ss, N);
    csr_fill_kernel<<<(E + 255) / 256, 256, 0, stream>>>(
        src, dst, off, cursor, csr_s, csr_d, csr_e, E);

    // ---- fused-weight precompute (exact f32) + bf16 hi/lo conversion ----
    mm2_kernel<<<256, 128, 0, stream>>>(Wmsg, Wupd, M12);
    cvec_kernel<<<1, 128, 0, stream>>>(bmsg, Wupd, cvec);
    wft_build_kernel<<<192, 256, 0, stream>>>(Wupd, M12, wft_hi, wft_lo);
    wt_convert_kernel<<<128, 256, 0, stream>>>(We1, wte_hi, wte_lo, 256, 128);
    wt_convert_kernel<<<32,  256, 0, stream>>>(We2, w2t_hi, w2t_lo, 128, 64);

    // ---- encoder ----
    encoder_kernel<<<(N + 1) / 2, 256, 0, stream>>>(x, Wenc, benc, h0, N);

    // ---- GNN layers: pull + ONE fused GEMM per layer ----
    const int gblocks = (N + 63) / 64;
    float* hc = h0;
    float* hn = h1;
    for (int l = 0; l < 3; ++l) {
        pull_kernel<<<(N + 3) / 4, 256, 0, stream>>>(hc, off, csr_s, rs, S, N);
        gemm_fused_kernel<<<gblocks, 256, 0, stream>>>(
            hc, S, ss, wft_hi, wft_lo, bupd, cvec, hn, N);
        float* t = hc; hc = hn; hn = t;
    }

    // ---- P/Q precompute for edge head ----
    float* Pb = S;
    gemm_mfma_kernel<<<gblocks, 256, 0, stream>>>(
        hc, nullptr, nullptr, wte_hi, wte_lo, 256, 0, nullptr, nullptr, Pb, N, 128, 0);
    gemm_mfma_kernel<<<gblocks, 256, 0, stream>>>(
        hc, nullptr, nullptr, wte_hi, wte_lo, 256, 128, nullptr, nullptr, Qb, N, 128, 0);

    // ---- heads ----
    node_head_kernel<<<(N + 3) / 4, 256, 0, stream>>>(
        hc, Wn1, bn1, Wn2, bn2, node_out, N);
    edge_head_kernel<<<(E + 63) / 64, 256, 0, stream>>>(
        Pb, Qb, csr_s, csr_d, csr_e, eattr, We1 + (size_t)256 * HD, be1,
        w2t_hi, w2t_lo, be2, We3, be3, edge_out, E);
}

// Round 10
// 863.239 us; speedup vs baseline: 1.4139x; 1.0922x over previous
//
#include <hip/hip_runtime.h>
#include <hip/hip_bf16.h>

#define HD 128   // hidden size

typedef __attribute__((ext_vector_type(8))) short bf16x8;
typedef __attribute__((ext_vector_type(4))) float f32x4;

__device__ __forceinline__ ushort f2bf(float f) {
    uint u = __float_as_uint(f);
    return (ushort)((u + 0x7FFFu + ((u >> 16) & 1u)) >> 16);
}
__device__ __forceinline__ float bf2f(ushort h) {
    return __uint_as_float(((uint)h) << 16);
}

// ---------------- encoder: h = x @ W_enc + b_enc ----------------
__global__ __launch_bounds__(256) void encoder_kernel(
    const float* __restrict__ x, const float* __restrict__ W,
    const float* __restrict__ b, float* __restrict__ h, int N)
{
    int n = blockIdx.x * 2 + (threadIdx.x >> 7);
    int c = threadIdx.x & 127;
    if (n >= N) return;
    const float* xr = x + (size_t)n * 16;
    float acc = b[c];
#pragma unroll
    for (int k = 0; k < 16; ++k)
        acc = fmaf(xr[k], W[k * HD + c], acc);
    h[(size_t)n * HD + c] = acc;
}

// ---------------- int degree histogram ----------------
__global__ __launch_bounds__(256) void deg_int_kernel(
    const int* __restrict__ dst, int* __restrict__ deg, int E)
{
    int e = blockIdx.x * 256 + threadIdx.x;
    if (e < E) atomicAdd(&deg[dst[e]], 1);
}

// r = 1/max(cnt,1), s = cnt/max(cnt,1)
__global__ __launch_bounds__(256) void degscale_kernel(
    const int* __restrict__ deg, float* __restrict__ r,
    float* __restrict__ s, int N)
{
    int n = blockIdx.x * 256 + threadIdx.x;
    if (n < N) {
        float c = (float)deg[n];
        float cp = fmaxf(c, 1.0f);
        r[n] = 1.0f / cp;
        s[n] = c / cp;
    }
}

// ---------------- single-block exclusive scan ----------------
__global__ __launch_bounds__(256) void scan_kernel(
    const int* __restrict__ deg, int* __restrict__ off, int N)
{
    __shared__ int wsum[4];
    const int tid = threadIdx.x;
    const int lane = tid & 63;
    const int wid = tid >> 6;
    int carry = 0;
    for (int base = 0; base < N; base += 256) {
        int i = base + tid;
        int v = (i < N) ? deg[i] : 0;
        int x = v;
#pragma unroll
        for (int d = 1; d < 64; d <<= 1) {
            int y = __shfl_up(x, d);
            if (lane >= d) x += y;
        }
        if (lane == 63) wsum[wid] = x;
        __syncthreads();
        int add = 0;
#pragma unroll
        for (int w = 0; w < 3; ++w)
            if (w < wid) add += wsum[w];
        if (i < N) off[i] = carry + add + x - v;
        carry += wsum[0] + wsum[1] + wsum[2] + wsum[3];
        __syncthreads();
    }
    if (tid == 0) off[N] = carry;
}

// ---------------- CSR fill: slot -> (src, dst, eid) ----------------
__global__ __launch_bounds__(256) void csr_fill_kernel(
    const int* __restrict__ src, const int* __restrict__ dst,
    const int* __restrict__ off, int* __restrict__ cursor,
    int* __restrict__ csr_src, int* __restrict__ csr_dst,
    int* __restrict__ csr_eid, int E)
{
    int e = blockIdx.x * 256 + threadIdx.x;
    if (e < E) {
        int d = dst[e];
        int p = atomicAdd(&cursor[d], 1);
        int pos = off[d] + p;
        csr_src[pos] = src[e];
        csr_dst[pos] = d;
        csr_eid[pos] = e;
    }
}

// ---------------- pull aggregation: S[n] = r[n] * sum h[src_e] ----------------
// unroll-by-4: 4 independent row gathers in flight per wave
__global__ __launch_bounds__(256) void pull_kernel(
    const float* __restrict__ h, const int* __restrict__ off,
    const int* __restrict__ csr, const float* __restrict__ r,
    float* __restrict__ S, int N)
{
    int n = blockIdx.x * 4 + (threadIdx.x >> 6);
    if (n >= N) return;
    int lane = threadIdx.x & 63;
    int beg = off[n], end = off[n + 1];
    float ax = 0.0f, ay = 0.0f;
    int i = beg;
    for (; i + 3 < end; i += 4) {
        int s0 = csr[i], s1 = csr[i + 1], s2 = csr[i + 2], s3 = csr[i + 3];
        float2 v0 = *reinterpret_cast<const float2*>(h + (size_t)s0 * HD + 2 * lane);
        float2 v1 = *reinterpret_cast<const float2*>(h + (size_t)s1 * HD + 2 * lane);
        float2 v2 = *reinterpret_cast<const float2*>(h + (size_t)s2 * HD + 2 * lane);
        float2 v3 = *reinterpret_cast<const float2*>(h + (size_t)s3 * HD + 2 * lane);
        ax += (v0.x + v1.x) + (v2.x + v3.x);
        ay += (v0.y + v1.y) + (v2.y + v3.y);
    }
    for (; i < end; ++i) {
        int s = csr[i];
        float2 v = *reinterpret_cast<const float2*>(h + (size_t)s * HD + 2 * lane);
        ax += v.x; ay += v.y;
    }
    float rr = r[n];
    *reinterpret_cast<float2*>(S + (size_t)n * HD + 2 * lane) =
        make_float2(ax * rr, ay * rr);
}

// ---------------- M12 = [Wm_top@Wu_bot ; Wm_bot@Wu_bot] (f32 exact) ----------------
__global__ __launch_bounds__(128) void mm2_kernel(
    const float* __restrict__ Wmsg, const float* __restrict__ Wupd,
    float* __restrict__ M)
{
    int b = blockIdx.x;              // 0..255
    int j = threadIdx.x;             // 0..127
    const float* Ar = Wmsg + (size_t)b * 128;
    const float* B  = Wupd + 128 * 128;           // Wu_bot
    float acc = 0.0f;
#pragma unroll 8
    for (int k = 0; k < 128; ++k)
        acc = fmaf(Ar[k], B[k * 128 + j], acc);
    M[(size_t)b * 128 + j] = acc;
}

// cvec = bmsg @ Wu_bot
__global__ __launch_bounds__(128) void cvec_kernel(
    const float* __restrict__ bmsg, const float* __restrict__ Wupd,
    float* __restrict__ cvec)
{
    int j = threadIdx.x;
    const float* B = Wupd + 128 * 128;
    float acc = 0.0f;
#pragma unroll 8
    for (int k = 0; k < 128; ++k)
        acc = fmaf(bmsg[k], B[k * 128 + j], acc);
    cvec[j] = acc;
}

// ---------------- build fused W'T [c][384] bf16 hi/lo ----------------
__global__ __launch_bounds__(256) void wft_build_kernel(
    const float* __restrict__ Wupd, const float* __restrict__ M12,
    ushort* __restrict__ WThi, ushort* __restrict__ WTlo)
{
    int idx = blockIdx.x * 256 + threadIdx.x;
    if (idx >= 384 * 128) return;
    int k = idx >> 7, c = idx & 127;
    float a = (k < 128) ? Wupd[idx] : M12[(size_t)(k - 128) * 128 + c];
    ushort hi = f2bf(a);
    ushort lo = f2bf(a - bf2f(hi));
    WThi[(size_t)c * 384 + k] = hi;
    WTlo[(size_t)c * 384 + k] = lo;
}

// ---------------- W[K][C] -> transposed bf16 hi/lo: WT[c][k] ----------------
__global__ __launch_bounds__(256) void wt_convert_kernel(
    const float* __restrict__ W, ushort* __restrict__ WThi,
    ushort* __restrict__ WTlo, int K, int C)
{
    int idx = blockIdx.x * 256 + threadIdx.x;
    if (idx >= K * C) return;
    int k = idx / C, c = idx % C;
    float a = W[idx];
    ushort hi = f2bf(a);
    ushort lo = f2bf(a - bf2f(hi));
    WThi[c * K + k] = hi;
    WTlo[c * K + k] = lo;
}

// ---------------- fused layer GEMM: h' = relu([h|S|s*h] @ W' + b_upd + s*cvec) ----------------
__global__ __launch_bounds__(256) void gemm_fused_kernel(
    const float* __restrict__ h, const float* __restrict__ S,
    const float* __restrict__ ss,
    const ushort* __restrict__ WT_hi, const ushort* __restrict__ WT_lo,
    const float* __restrict__ bupd, const float* __restrict__ cvec,
    float* __restrict__ out, int N)
{
    __shared__ __align__(16) ushort Ahi_s[64][40];
    __shared__ __align__(16) ushort Alo_s[64][40];
    __shared__ __align__(16) ushort Bhi_s[128][40];
    __shared__ __align__(16) ushort Blo_s[128][40];

    const int tid    = threadIdx.x;
    const int n_base = blockIdx.x * 64;
    const int sa_row = tid >> 2;
    const int sa_k4  = (tid & 3) * 4;
    const int sa_ng  = min(n_base + sa_row, N - 1);
    const float scA  = ss[sa_ng];
    const int sb_c = tid & 127;
    const int sb_h = (tid >> 7) * 16;
    const int lane = tid & 63, wv = tid >> 6;
    const int fr = lane & 15;
    const int fk = (lane >> 4) * 8;

    f32x4 acc[8];
#pragma unroll
    for (int t = 0; t < 8; ++t) acc[t] = (f32x4){0.f, 0.f, 0.f, 0.f};

    for (int s = 0; s < 12; ++s) {
        const int k0 = s * 32;
        __syncthreads();
        const int part = k0 >> 7;            // 0: h, 1: S, 2: s*h
        const int kof  = k0 & 127;
        const float* Ab = (part == 1) ? S : h;
        const float  sc = (part == 2) ? scA : 1.0f;
#pragma unroll
        for (int ch = 0; ch < 32; ch += 16) {
            float4 v = *reinterpret_cast<const float4*>(
                Ab + (size_t)sa_ng * HD + kof + ch + sa_k4);
            float vv[4] = {v.x * sc, v.y * sc, v.z * sc, v.w * sc};
            ushort4 hi, lo;
            hi.x = f2bf(vv[0]); lo.x = f2bf(vv[0] - bf2f(hi.x));
            hi.y = f2bf(vv[1]); lo.y = f2bf(vv[1] - bf2f(hi.y));
            hi.z = f2bf(vv[2]); lo.z = f2bf(vv[2] - bf2f(hi.z));
            hi.w = f2bf(vv[3]); lo.w = f2bf(vv[3] - bf2f(hi.w));
            *reinterpret_cast<ushort4*>(&Ahi_s[sa_row][ch + sa_k4]) = hi;
            *reinterpret_cast<ushort4*>(&Alo_s[sa_row][ch + sa_k4]) = lo;
        }
        {
            const ushort* ph = WT_hi + (size_t)sb_c * 384 + k0 + sb_h;
            const ushort* pl = WT_lo + (size_t)sb_c * 384 + k0 + sb_h;
            *reinterpret_cast<uint4*>(&Bhi_s[sb_c][sb_h])     = *reinterpret_cast<const uint4*>(ph);
            *reinterpret_cast<uint4*>(&Bhi_s[sb_c][sb_h + 8]) = *reinterpret_cast<const uint4*>(ph + 8);
            *reinterpret_cast<uint4*>(&Blo_s[sb_c][sb_h])     = *reinterpret_cast<const uint4*>(pl);
            *reinterpret_cast<uint4*>(&Blo_s[sb_c][sb_h + 8]) = *reinterpret_cast<const uint4*>(pl + 8);
        }
        __syncthreads();
        bf16x8 ah = *reinterpret_cast<bf16x8*>(&Ahi_s[wv * 16 + fr][fk]);
        bf16x8 al = *reinterpret_cast<bf16x8*>(&Alo_s[wv * 16 + fr][fk]);
#pragma unroll
        for (int t = 0; t < 8; ++t) {
            bf16x8 bh = *reinterpret_cast<bf16x8*>(&Bhi_s[t * 16 + fr][fk]);
            bf16x8 bl = *reinterpret_cast<bf16x8*>(&Blo_s[t * 16 + fr][fk]);
            acc[t] = __builtin_amdgcn_mfma_f32_16x16x32_bf16(ah, bh, acc[t], 0, 0, 0);
            acc[t] = __builtin_amdgcn_mfma_f32_16x16x32_bf16(al, bh, acc[t], 0, 0, 0);
            acc[t] = __builtin_amdgcn_mfma_f32_16x16x32_bf16(ah, bl, acc[t], 0, 0, 0);
        }
    }
#pragma unroll
    for (int reg = 0; reg < 4; ++reg) {
        int n = n_base + wv * 16 + (lane >> 4) * 4 + reg;
        if (n < N) {
            float sv = ss[n];
#pragma unroll
            for (int t = 0; t < 8; ++t) {
                int c = t * 16 + fr;
                float v = acc[t][reg] + bupd[c] + sv * cvec[c];
                out[(size_t)n * HD + c] = fmaxf(v, 0.0f);
            }
        }
    }
}

// ---------------- split-bf16 MFMA GEMM (r4-proven; used for P/Q, K=128) ----------------
__global__ __launch_bounds__(256) void gemm_mfma_kernel(
    const float* __restrict__ A0, const float* __restrict__ A1,
    const float* __restrict__ s1,
    const ushort* __restrict__ WT_hi, const ushort* __restrict__ WT_lo,
    int wstride, int kw0,
    const float* __restrict__ bias, const float* __restrict__ bscale,
    float* __restrict__ out, int N, int K, int relu)
{
    __shared__ __align__(16) ushort Ahi_s[64][40];
    __shared__ __align__(16) ushort Alo_s[64][40];
    __shared__ __align__(16) ushort Bhi_s[128][40];
    __shared__ __align__(16) ushort Blo_s[128][40];

    const int tid    = threadIdx.x;
    const int n_base = blockIdx.x * 64;
    const int sa_row = tid >> 2;
    const int sa_k4  = (tid & 3) * 4;
    const int sa_ng  = min(n_base + sa_row, N - 1);
    const float scA1 = s1 ? s1[sa_ng] : 1.0f;
    const int sb_c = tid & 127;
    const int sb_h = (tid >> 7) * 16;
    const int lane = tid & 63, wv = tid >> 6;
    const int fr = lane & 15;
    const int fk = (lane >> 4) * 8;

    f32x4 acc[8];
#pragma unroll
    for (int t = 0; t < 8; ++t) acc[t] = (f32x4){0.f, 0.f, 0.f, 0.f};

    const int nsteps = K >> 5;
    for (int s = 0; s < nsteps; ++s) {
        const int k0 = s * 32;
        __syncthreads();
        const float* Ab; int kof; float sc;
        if (K == 256 && k0 >= 128) { Ab = A1; kof = k0 - 128; sc = scA1; }
        else                       { Ab = A0; kof = k0;       sc = 1.0f; }
#pragma unroll
        for (int ch = 0; ch < 32; ch += 16) {
            float4 v = *reinterpret_cast<const float4*>(
                Ab + (size_t)sa_ng * HD + kof + ch + sa_k4);
            float vv[4] = {v.x * sc, v.y * sc, v.z * sc, v.w * sc};
            ushort4 hi, lo;
            hi.x = f2bf(vv[0]); lo.x = f2bf(vv[0] - bf2f(hi.x));
            hi.y = f2bf(vv[1]); lo.y = f2bf(vv[1] - bf2f(hi.y));
            hi.z = f2bf(vv[2]); lo.z = f2bf(vv[2] - bf2f(hi.z));
            hi.w = f2bf(vv[3]); lo.w = f2bf(vv[3] - bf2f(hi.w));
            *reinterpret_cast<ushort4*>(&Ahi_s[sa_row][ch + sa_k4]) = hi;
            *reinterpret_cast<ushort4*>(&Alo_s[sa_row][ch + sa_k4]) = lo;
        }
        {
            const ushort* ph = WT_hi + (size_t)sb_c * wstride + kw0 + k0 + sb_h;
            const ushort* pl = WT_lo + (size_t)sb_c * wstride + kw0 + k0 + sb_h;
            *reinterpret_cast<uint4*>(&Bhi_s[sb_c][sb_h])     = *reinterpret_cast<const uint4*>(ph);
            *reinterpret_cast<uint4*>(&Bhi_s[sb_c][sb_h + 8]) = *reinterpret_cast<const uint4*>(ph + 8);
            *reinterpret_cast<uint4*>(&Blo_s[sb_c][sb_h])     = *reinterpret_cast<const uint4*>(pl);
            *reinterpret_cast<uint4*>(&Blo_s[sb_c][sb_h + 8]) = *reinterpret_cast<const uint4*>(pl + 8);
        }
        __syncthreads();
        bf16x8 ah = *reinterpret_cast<bf16x8*>(&Ahi_s[wv * 16 + fr][fk]);
        bf16x8 al = *reinterpret_cast<bf16x8*>(&Alo_s[wv * 16 + fr][fk]);
#pragma unroll
        for (int t = 0; t < 8; ++t) {
            bf16x8 bh = *reinterpret_cast<bf16x8*>(&Bhi_s[t * 16 + fr][fk]);
            bf16x8 bl = *reinterpret_cast<bf16x8*>(&Blo_s[t * 16 + fr][fk]);
            acc[t] = __builtin_amdgcn_mfma_f32_16x16x32_bf16(ah, bh, acc[t], 0, 0, 0);
            acc[t] = __builtin_amdgcn_mfma_f32_16x16x32_bf16(al, bh, acc[t], 0, 0, 0);
            acc[t] = __builtin_amdgcn_mfma_f32_16x16x32_bf16(ah, bl, acc[t], 0, 0, 0);
        }
    }
#pragma unroll
    for (int reg = 0; reg < 4; ++reg) {
        int n = n_base + wv * 16 + (lane >> 4) * 4 + reg;
        if (n < N) {
            float bs = bscale ? bscale[n] : 1.0f;
#pragma unroll
            for (int t = 0; t < 8; ++t) {
                int c = t * 16 + fr;
                float v = acc[t][reg] + (bias ? bias[c] * bs : 0.0f);
                out[(size_t)n * HD + c] = relu ? fmaxf(v, 0.0f) : v;
            }
        }
    }
}

// ---------------- node head ----------------
__global__ __launch_bounds__(256) void node_head_kernel(
    const float* __restrict__ h,
    const float* __restrict__ W1, const float* __restrict__ b1,
    const float* __restrict__ W2, const float* __restrict__ b2,
    float* __restrict__ out, int N)
{
    int n = blockIdx.x * 4 + (threadIdx.x >> 6);
    int lane = threadIdx.x & 63;
    if (n >= N) return;
    const float* hr = h + (size_t)n * HD;
    float t = b1[lane];
#pragma unroll 16
    for (int k = 0; k < HD; ++k)
        t = fmaf(hr[k], W1[k * 64 + lane], t);
    t = fmaxf(t, 0.0f);
    float o0 = t * W2[lane * 2 + 0];
    float o1 = t * W2[lane * 2 + 1];
#pragma unroll
    for (int sft = 32; sft > 0; sft >>= 1) {
        o0 += __shfl_xor(o0, sft);
        o1 += __shfl_xor(o1, sft);
    }
    if (lane == 0) {
        out[(size_t)n * 2 + 0] = o0 + b2[0];
        out[(size_t)n * 2 + 1] = o1 + b2[1];
    }
}

// ---------------- fused edge head, CSR-ordered, all-register t1 (r6-proven) ----------------
__global__ __launch_bounds__(256) void edge_head_kernel(
    const float* __restrict__ P, const float* __restrict__ Q,
    const int* __restrict__ csr_src, const int* __restrict__ csr_dst,
    const int* __restrict__ csr_eid,
    const float* __restrict__ ea,
    const float* __restrict__ W1c, const float* __restrict__ b1,
    const ushort* __restrict__ W2Th, const ushort* __restrict__ W2Tl,  // [64][128]
    const float* __restrict__ b2,
    const float* __restrict__ W3, const float* __restrict__ b3,
    float* __restrict__ out, int E)
{
    const int tid  = threadIdx.x;
    const int base = blockIdx.x * 64;
    const int lane = tid & 63, wv = tid >> 6;
    const int fr = lane & 15;          // edge within wave-tile / output col idx
    const int hi16 = lane >> 4;        // 0..3
    const int fk = hi16 * 8;           // k-offset within 32-chunk

    // ---- phase 1: build this lane's A-fragments in registers ----
    const int slot = min(base + wv * 16 + fr, E - 1);
    const int sn  = csr_src[slot];
    const int dn  = csr_dst[slot];
    const int eid = csr_eid[slot];

    float eav[8];
    {
        float4 e0 = *reinterpret_cast<const float4*>(ea + (size_t)eid * 8);
        float4 e1 = *reinterpret_cast<const float4*>(ea + (size_t)eid * 8 + 4);
        eav[0] = e0.x; eav[1] = e0.y; eav[2] = e0.z; eav[3] = e0.w;
        eav[4] = e1.x; eav[5] = e1.y; eav[6] = e1.z; eav[7] = e1.w;
    }

    bf16x8 ah[4], al[4];
#pragma unroll
    for (int kt = 0; kt < 4; ++kt) {
        const int c0 = kt * 32 + fk;
        float4 p0 = *reinterpret_cast<const float4*>(P + (size_t)sn * HD + c0);
        float4 p1 = *reinterpret_cast<const float4*>(P + (size_t)sn * HD + c0 + 4);
        float4 q0 = *reinterpret_cast<const float4*>(Q + (size_t)dn * HD + c0);
        float4 q1 = *reinterpret_cast<const float4*>(Q + (size_t)dn * HD + c0 + 4);
        float4 b0 = *reinterpret_cast<const float4*>(b1 + c0);
        float4 b1v = *reinterpret_cast<const float4*>(b1 + c0 + 4);
        float v[8];
        v[0] = p0.x + q0.x + b0.x;  v[1] = p0.y + q0.y + b0.y;
        v[2] = p0.z + q0.z + b0.z;  v[3] = p0.w + q0.w + b0.w;
        v[4] = p1.x + q1.x + b1v.x; v[5] = p1.y + q1.y + b1v.y;
        v[6] = p1.z + q1.z + b1v.z; v[7] = p1.w + q1.w + b1v.w;
#pragma unroll
        for (int k = 0; k < 8; ++k) {
            float4 w0 = *reinterpret_cast<const float4*>(W1c + k * HD + c0);
            float4 w1 = *reinterpret_cast<const float4*>(W1c + k * HD + c0 + 4);
            v[0] = fmaf(eav[k], w0.x, v[0]); v[1] = fmaf(eav[k], w0.y, v[1]);
            v[2] = fmaf(eav[k], w0.z, v[2]); v[3] = fmaf(eav[k], w0.w, v[3]);
            v[4] = fmaf(eav[k], w1.x, v[4]); v[5] = fmaf(eav[k], w1.y, v[5]);
            v[6] = fmaf(eav[k], w1.z, v[6]); v[7] = fmaf(eav[k], w1.w, v[7]);
        }
#pragma unroll
        for (int j = 0; j < 8; ++j) {
            float t = fmaxf(v[j], 0.0f);
            ushort h = f2bf(t);
            ushort l = f2bf(t - bf2f(h));
            ah[kt][j] = (short)h;
            al[kt][j] = (short)l;
        }
    }

    // ---- phase 2: t2 = t1 @ W2 via MFMA (B frags from L2) ----
    f32x4 acc[4];
#pragma unroll
    for (int t = 0; t < 4; ++t) acc[t] = (f32x4){0.f, 0.f, 0.f, 0.f};
#pragma unroll
    for (int kt = 0; kt < 4; ++kt) {
#pragma unroll
        for (int t = 0; t < 4; ++t) {
            const size_t boff = (size_t)(t * 16 + fr) * 128 + kt * 32 + fk;
            bf16x8 bh = *reinterpret_cast<const bf16x8*>(W2Th + boff);
            bf16x8 bl = *reinterpret_cast<const bf16x8*>(W2Tl + boff);
            acc[t] = __builtin_amdgcn_mfma_f32_16x16x32_bf16(ah[kt], bh, acc[t], 0, 0, 0);
            acc[t] = __builtin_amdgcn_mfma_f32_16x16x32_bf16(al[kt], bh, acc[t], 0, 0, 0);
            acc[t] = __builtin_amdgcn_mfma_f32_16x16x32_bf16(ah[kt], bl, acc[t], 0, 0, 0);
        }
    }

    // ---- phase 3: out = relu(t2+b2) @ W3 + b3, in registers ----
    float b2v[4];
#pragma unroll
    for (int t = 0; t < 4; ++t) b2v[t] = b2[t * 16 + fr];
#pragma unroll
    for (int reg = 0; reg < 4; ++reg) {
        int erow = wv * 16 + hi16 * 4 + reg;
        float p[6];
#pragma unroll
        for (int j = 0; j < 6; ++j) p[j] = 0.0f;
#pragma unroll
        for (int t = 0; t < 4; ++t) {
            int c = t * 16 + fr;
            float t2v = fmaxf(acc[t][reg] + b2v[t], 0.0f);
#pragma unroll
            for (int j = 0; j < 6; ++j)
                p[j] = fmaf(t2v, W3[c * 6 + j], p[j]);
        }
#pragma unroll
        for (int j = 0; j < 6; ++j) {
#pragma unroll
            for (int sft = 1; sft < 16; sft <<= 1)
                p[j] += __shfl_xor(p[j], sft);
        }
        int oslot = base + erow;
        if (fr < 6 && oslot < E) {
            int oeid = csr_eid[oslot];
            out[(size_t)oeid * 6 + fr] = p[fr] + b3[fr];
        }
    }
}

// ---------------- launch ----------------
extern "C" void kernel_launch(void* const* d_in, const int* in_sizes, int n_in,
                              void* d_out, int out_size, void* d_ws, size_t ws_size,
                              hipStream_t stream)
{
    (void)n_in; (void)out_size; (void)ws_size;
    const float* x     = (const float*)d_in[0];
    const int*   ei    = (const int*)d_in[1];
    const float* eattr = (const float*)d_in[2];
    const float* Wenc = (const float*)d_in[4];
    const float* benc = (const float*)d_in[5];
    const float* Wmsg = (const float*)d_in[6];
    const float* bmsg = (const float*)d_in[7];
    const float* Wupd = (const float*)d_in[8];
    const float* bupd = (const float*)d_in[9];
    const float* Wn1  = (const float*)d_in[10];
    const float* bn1  = (const float*)d_in[11];
    const float* Wn2  = (const float*)d_in[12];
    const float* bn2  = (const float*)d_in[13];
    const float* We1  = (const float*)d_in[14];
    const float* be1  = (const float*)d_in[15];
    const float* We2  = (const float*)d_in[16];
    const float* be2  = (const float*)d_in[17];
    const float* We3  = (const float*)d_in[18];
    const float* be3  = (const float*)d_in[19];

    const int N = in_sizes[0] / 16;
    const int E = in_sizes[1] / 2;
    const int* src = ei;
    const int* dst = ei + E;

    float* h0   = (float*)d_ws;
    float* h1   = h0 + (size_t)N * HD;
    float* S    = h1 + (size_t)N * HD;     // pull target; later reused as P
    float* Qb   = S  + (size_t)N * HD;     // later Q
    float* rs   = Qb + (size_t)N * HD;
    float* ss   = rs + N;
    int* deg_i  = (int*)(ss + N);
    int* off    = deg_i + N;               // N+1
    int* cursor = off + N + 1;
    int* csr_s  = cursor + N;              // E
    int* csr_d  = csr_s + E;               // E
    int* csr_e  = csr_d + E;               // E
    float* fM   = (float*)(((uintptr_t)(csr_e + E) + 255) & ~(uintptr_t)255);
    float* M12  = fM;                      // 256*128
    float* cvec = fM + 32768;              // 128
    ushort* wt  = (ushort*)(cvec + 128);
    ushort* wft_hi = wt;                   // 128*384
    ushort* wft_lo = wft_hi + 49152;
    ushort* wte_hi = wft_lo + 49152;       // 128*256
    ushort* wte_lo = wte_hi + 32768;
    ushort* w2t_hi = wte_lo + 32768;       // 64*128
    ushort* w2t_lo = w2t_hi + 8192;

    float* node_out = (float*)d_out;
    float* edge_out = node_out + (size_t)N * 2;

    // ---- CSR build ----
    hipMemsetAsync(deg_i, 0, (size_t)N * sizeof(int), stream);
    hipMemsetAsync(cursor, 0, (size_t)N * sizeof(int), stream);
    deg_int_kernel<<<(E + 255) / 256, 256, 0, stream>>>(dst, deg_i, E);
    scan_kernel<<<1, 256, 0, stream>>>(deg_i, off, N);
    degscale_kernel<<<(N + 255) / 256, 256, 0, stream>>>(deg_i, rs, ss, N);
    csr_fill_kernel<<<(E + 255) / 256, 256, 0, stream>>>(
        src, dst, off, cursor, csr_s, csr_d, csr_e, E);

    // ---- fused-weight precompute (exact f32) + bf16 hi/lo conversion ----
    mm2_kernel<<<256, 128, 0, stream>>>(Wmsg, Wupd, M12);
    cvec_kernel<<<1, 128, 0, stream>>>(bmsg, Wupd, cvec);
    wft_build_kernel<<<192, 256, 0, stream>>>(Wupd, M12, wft_hi, wft_lo);
    wt_convert_kernel<<<128, 256, 0, stream>>>(We1, wte_hi, wte_lo, 256, 128);
    wt_convert_kernel<<<32,  256, 0, stream>>>(We2, w2t_hi, w2t_lo, 128, 64);

    // ---- encoder ----
    encoder_kernel<<<(N + 1) / 2, 256, 0, stream>>>(x, Wenc, benc, h0, N);

    // ---- GNN layers: pull + ONE fused GEMM per layer ----
    const int gblocks = (N + 63) / 64;
    float* hc = h0;
    float* hn = h1;
    for (int l = 0; l < 3; ++l) {
        pull_kernel<<<(N + 3) / 4, 256, 0, stream>>>(hc, off, csr_s, rs, S, N);
        gemm_fused_kernel<<<gblocks, 256, 0, stream>>>(
            hc, S, ss, wft_hi, wft_lo, bupd, cvec, hn, N);
        float* t = hc; hc = hn; hn = t;
    }

    // ---- P/Q precompute for edge head ----
    float* Pb = S;
    gemm_mfma_kernel<<<gblocks, 256, 0, stream>>>(
        hc, nullptr, nullptr, wte_hi, wte_lo, 256, 0, nullptr, nullptr, Pb, N, 128, 0);
    gemm_mfma_kernel<<<gblocks, 256, 0, stream>>>(
        hc, nullptr, nullptr, wte_hi, wte_lo, 256, 128, nullptr, nullptr, Qb, N, 128, 0);

    // ---- heads ----
    node_head_kernel<<<(N + 3) / 4, 256, 0, stream>>>(
        hc, Wn1, bn1, Wn2, bn2, node_out, N);
    edge_head_kernel<<<(E + 63) / 64, 256, 0, stream>>>(
        Pb, Qb, csr_s, csr_d, csr_e, eattr, We1 + (size_t)256 * HD, be1,
        w2t_hi, w2t_lo, be2, We3, be3, edge_out, E);
}

// Round 11
// 794.636 us; speedup vs baseline: 1.5359x; 1.0863x over previous
//
#include <hip/hip_runtime.h>
#include <hip/hip_bf16.h>

#define HD 128   // hidden size

typedef __attribute__((ext_vector_type(8))) short bf16x8;
typedef __attribute__((ext_vector_type(4))) float f32x4;

__device__ __forceinline__ ushort f2bf(float f) {
    uint u = __float_as_uint(f);
    return (ushort)((u + 0x7FFFu + ((u >> 16) & 1u)) >> 16);
}
__device__ __forceinline__ float bf2f(ushort h) {
    return __uint_as_float(((uint)h) << 16);
}

// ---------------- encoder: h = x @ W_enc + b_enc ----------------
__global__ __launch_bounds__(256) void encoder_kernel(
    const float* __restrict__ x, const float* __restrict__ W,
    const float* __restrict__ b, float* __restrict__ h, int N)
{
    int n = blockIdx.x * 2 + (threadIdx.x >> 7);
    int c = threadIdx.x & 127;
    if (n >= N) return;
    const float* xr = x + (size_t)n * 16;
    float acc = b[c];
#pragma unroll
    for (int k = 0; k < 16; ++k)
        acc = fmaf(xr[k], W[k * HD + c], acc);
    h[(size_t)n * HD + c] = acc;
}

// ---------------- int degree histogram ----------------
__global__ __launch_bounds__(256) void deg_int_kernel(
    const int* __restrict__ dst, int* __restrict__ deg, int E)
{
    int e = blockIdx.x * 256 + threadIdx.x;
    if (e < E) atomicAdd(&deg[dst[e]], 1);
}

// r = 1/max(cnt,1), s = cnt/max(cnt,1)
__global__ __launch_bounds__(256) void degscale_kernel(
    const int* __restrict__ deg, float* __restrict__ r,
    float* __restrict__ s, int N)
{
    int n = blockIdx.x * 256 + threadIdx.x;
    if (n < N) {
        float c = (float)deg[n];
        float cp = fmaxf(c, 1.0f);
        r[n] = 1.0f / cp;
        s[n] = c / cp;
    }
}

// ---------------- single-block exclusive scan (1024 threads) ----------------
__global__ __launch_bounds__(1024) void scan_kernel(
    const int* __restrict__ deg, int* __restrict__ off, int N)
{
    __shared__ int wsum[16];
    const int tid = threadIdx.x;
    const int lane = tid & 63;
    const int wid = tid >> 6;
    int carry = 0;
    for (int base = 0; base < N; base += 1024) {
        int i = base + tid;
        int v = (i < N) ? deg[i] : 0;
        int x = v;
#pragma unroll
        for (int d = 1; d < 64; d <<= 1) {
            int y = __shfl_up(x, d);
            if (lane >= d) x += y;
        }
        if (lane == 63) wsum[wid] = x;
        __syncthreads();
        int add = 0;
#pragma unroll
        for (int w = 0; w < 15; ++w)
            if (w < wid) add += wsum[w];
        if (i < N) off[i] = carry + add + x - v;
        int tot = 0;
#pragma unroll
        for (int w = 0; w < 16; ++w) tot += wsum[w];
        carry += tot;
        __syncthreads();
    }
    if (tid == 0) off[N] = carry;
}

// ---------------- CSR fill: slot -> (src, dst, eid) ----------------
__global__ __launch_bounds__(256) void csr_fill_kernel(
    const int* __restrict__ src, const int* __restrict__ dst,
    const int* __restrict__ off, int* __restrict__ cursor,
    int* __restrict__ csr_src, int* __restrict__ csr_dst,
    int* __restrict__ csr_eid, int E)
{
    int e = blockIdx.x * 256 + threadIdx.x;
    if (e < E) {
        int d = dst[e];
        int p = atomicAdd(&cursor[d], 1);
        int pos = off[d] + p;
        csr_src[pos] = src[e];
        csr_dst[pos] = d;
        csr_eid[pos] = e;
    }
}

// ---------------- pull aggregation: S[n] = r[n] * sum h[src_e] ----------------
// unroll-by-4: 4 independent row gathers in flight per wave
__global__ __launch_bounds__(256) void pull_kernel(
    const float* __restrict__ h, const int* __restrict__ off,
    const int* __restrict__ csr, const float* __restrict__ r,
    float* __restrict__ S, int N)
{
    int n = blockIdx.x * 4 + (threadIdx.x >> 6);
    if (n >= N) return;
    int lane = threadIdx.x & 63;
    int beg = off[n], end = off[n + 1];
    float ax = 0.0f, ay = 0.0f;
    int i = beg;
    for (; i + 3 < end; i += 4) {
        int s0 = csr[i], s1 = csr[i + 1], s2 = csr[i + 2], s3 = csr[i + 3];
        float2 v0 = *reinterpret_cast<const float2*>(h + (size_t)s0 * HD + 2 * lane);
        float2 v1 = *reinterpret_cast<const float2*>(h + (size_t)s1 * HD + 2 * lane);
        float2 v2 = *reinterpret_cast<const float2*>(h + (size_t)s2 * HD + 2 * lane);
        float2 v3 = *reinterpret_cast<const float2*>(h + (size_t)s3 * HD + 2 * lane);
        ax += (v0.x + v1.x) + (v2.x + v3.x);
        ay += (v0.y + v1.y) + (v2.y + v3.y);
    }
    for (; i < end; ++i) {
        int s = csr[i];
        float2 v = *reinterpret_cast<const float2*>(h + (size_t)s * HD + 2 * lane);
        ax += v.x; ay += v.y;
    }
    float rr = r[n];
    *reinterpret_cast<float2*>(S + (size_t)n * HD + 2 * lane) =
        make_float2(ax * rr, ay * rr);
}

// ---------------- M12 = [Wm_top@Wu_bot ; Wm_bot@Wu_bot] (f32 exact) ----------------
__global__ __launch_bounds__(128) void mm2_kernel(
    const float* __restrict__ Wmsg, const float* __restrict__ Wupd,
    float* __restrict__ M)
{
    int b = blockIdx.x;              // 0..255
    int j = threadIdx.x;             // 0..127
    const float* Ar = Wmsg + (size_t)b * 128;
    const float* B  = Wupd + 128 * 128;           // Wu_bot
    float acc = 0.0f;
#pragma unroll 8
    for (int k = 0; k < 128; ++k)
        acc = fmaf(Ar[k], B[k * 128 + j], acc);
    M[(size_t)b * 128 + j] = acc;
}

// cvec = bmsg @ Wu_bot
__global__ __launch_bounds__(128) void cvec_kernel(
    const float* __restrict__ bmsg, const float* __restrict__ Wupd,
    float* __restrict__ cvec)
{
    int j = threadIdx.x;
    const float* B = Wupd + 128 * 128;
    float acc = 0.0f;
#pragma unroll 8
    for (int k = 0; k < 128; ++k)
        acc = fmaf(bmsg[k], B[k * 128 + j], acc);
    cvec[j] = acc;
}

// ---------------- build fused W'T [c][384] bf16 hi/lo ----------------
__global__ __launch_bounds__(256) void wft_build_kernel(
    const float* __restrict__ Wupd, const float* __restrict__ M12,
    ushort* __restrict__ WThi, ushort* __restrict__ WTlo)
{
    int idx = blockIdx.x * 256 + threadIdx.x;
    if (idx >= 384 * 128) return;
    int k = idx >> 7, c = idx & 127;
    float a = (k < 128) ? Wupd[idx] : M12[(size_t)(k - 128) * 128 + c];
    ushort hi = f2bf(a);
    ushort lo = f2bf(a - bf2f(hi));
    WThi[(size_t)c * 384 + k] = hi;
    WTlo[(size_t)c * 384 + k] = lo;
}

// ---------------- W[K][C] -> transposed bf16 hi/lo: WT[c][k] ----------------
__global__ __launch_bounds__(256) void wt_convert_kernel(
    const float* __restrict__ W, ushort* __restrict__ WThi,
    ushort* __restrict__ WTlo, int K, int C)
{
    int idx = blockIdx.x * 256 + threadIdx.x;
    if (idx >= K * C) return;
    int k = idx / C, c = idx % C;
    float a = W[idx];
    ushort hi = f2bf(a);
    ushort lo = f2bf(a - bf2f(hi));
    WThi[c * K + k] = hi;
    WTlo[c * K + k] = lo;
}

// ---------------- fused layer GEMM: h' = relu([h|S|s*h] @ W' + b_upd + s*cvec) ----------------
__global__ __launch_bounds__(256) void gemm_fused_kernel(
    const float* __restrict__ h, const float* __restrict__ S,
    const float* __restrict__ ss,
    const ushort* __restrict__ WT_hi, const ushort* __restrict__ WT_lo,
    const float* __restrict__ bupd, const float* __restrict__ cvec,
    float* __restrict__ out, int N)
{
    __shared__ __align__(16) ushort Ahi_s[64][40];
    __shared__ __align__(16) ushort Alo_s[64][40];
    __shared__ __align__(16) ushort Bhi_s[128][40];
    __shared__ __align__(16) ushort Blo_s[128][40];

    const int tid    = threadIdx.x;
    const int n_base = blockIdx.x * 64;
    const int sa_row = tid >> 2;
    const int sa_k4  = (tid & 3) * 4;
    const int sa_ng  = min(n_base + sa_row, N - 1);
    const float scA  = ss[sa_ng];
    const int sb_c = tid & 127;
    const int sb_h = (tid >> 7) * 16;
    const int lane = tid & 63, wv = tid >> 6;
    const int fr = lane & 15;
    const int fk = (lane >> 4) * 8;

    f32x4 acc[8];
#pragma unroll
    for (int t = 0; t < 8; ++t) acc[t] = (f32x4){0.f, 0.f, 0.f, 0.f};

    for (int s = 0; s < 12; ++s) {
        const int k0 = s * 32;
        __syncthreads();
        const int part = k0 >> 7;            // 0: h, 1: S, 2: s*h
        const int kof  = k0 & 127;
        const float* Ab = (part == 1) ? S : h;
        const float  sc = (part == 2) ? scA : 1.0f;
#pragma unroll
        for (int ch = 0; ch < 32; ch += 16) {
            float4 v = *reinterpret_cast<const float4*>(
                Ab + (size_t)sa_ng * HD + kof + ch + sa_k4);
            float vv[4] = {v.x * sc, v.y * sc, v.z * sc, v.w * sc};
            ushort4 hi, lo;
            hi.x = f2bf(vv[0]); lo.x = f2bf(vv[0] - bf2f(hi.x));
            hi.y = f2bf(vv[1]); lo.y = f2bf(vv[1] - bf2f(hi.y));
            hi.z = f2bf(vv[2]); lo.z = f2bf(vv[2] - bf2f(hi.z));
            hi.w = f2bf(vv[3]); lo.w = f2bf(vv[3] - bf2f(hi.w));
            *reinterpret_cast<ushort4*>(&Ahi_s[sa_row][ch + sa_k4]) = hi;
            *reinterpret_cast<ushort4*>(&Alo_s[sa_row][ch + sa_k4]) = lo;
        }
        {
            const ushort* ph = WT_hi + (size_t)sb_c * 384 + k0 + sb_h;
            const ushort* pl = WT_lo + (size_t)sb_c * 384 + k0 + sb_h;
            *reinterpret_cast<uint4*>(&Bhi_s[sb_c][sb_h])     = *reinterpret_cast<const uint4*>(ph);
            *reinterpret_cast<uint4*>(&Bhi_s[sb_c][sb_h + 8]) = *reinterpret_cast<const uint4*>(ph + 8);
            *reinterpret_cast<uint4*>(&Blo_s[sb_c][sb_h])     = *reinterpret_cast<const uint4*>(pl);
            *reinterpret_cast<uint4*>(&Blo_s[sb_c][sb_h + 8]) = *reinterpret_cast<const uint4*>(pl + 8);
        }
        __syncthreads();
        bf16x8 ah = *reinterpret_cast<bf16x8*>(&Ahi_s[wv * 16 + fr][fk]);
        bf16x8 al = *reinterpret_cast<bf16x8*>(&Alo_s[wv * 16 + fr][fk]);
#pragma unroll
        for (int t = 0; t < 8; ++t) {
            bf16x8 bh = *reinterpret_cast<bf16x8*>(&Bhi_s[t * 16 + fr][fk]);
            bf16x8 bl = *reinterpret_cast<bf16x8*>(&Blo_s[t * 16 + fr][fk]);
            acc[t] = __builtin_amdgcn_mfma_f32_16x16x32_bf16(ah, bh, acc[t], 0, 0, 0);
            acc[t] = __builtin_amdgcn_mfma_f32_16x16x32_bf16(al, bh, acc[t], 0, 0, 0);
            acc[t] = __builtin_amdgcn_mfma_f32_16x16x32_bf16(ah, bl, acc[t], 0, 0, 0);
        }
    }
#pragma unroll
    for (int reg = 0; reg < 4; ++reg) {
        int n = n_base + wv * 16 + (lane >> 4) * 4 + reg;
        if (n < N) {
            float sv = ss[n];
#pragma unroll
            for (int t = 0; t < 8; ++t) {
                int c = t * 16 + fr;
                float v = acc[t][reg] + bupd[c] + sv * cvec[c];
                out[(size_t)n * HD + c] = fmaxf(v, 0.0f);
            }
        }
    }
}

// ---------------- split-bf16 MFMA GEMM (r4-proven; used for P/Q, K=128) ----------------
__global__ __launch_bounds__(256) void gemm_mfma_kernel(
    const float* __restrict__ A0, const float* __restrict__ A1,
    const float* __restrict__ s1,
    const ushort* __restrict__ WT_hi, const ushort* __restrict__ WT_lo,
    int wstride, int kw0,
    const float* __restrict__ bias, const float* __restrict__ bscale,
    float* __restrict__ out, int N, int K, int relu)
{
    __shared__ __align__(16) ushort Ahi_s[64][40];
    __shared__ __align__(16) ushort Alo_s[64][40];
    __shared__ __align__(16) ushort Bhi_s[128][40];
    __shared__ __align__(16) ushort Blo_s[128][40];

    const int tid    = threadIdx.x;
    const int n_base = blockIdx.x * 64;
    const int sa_row = tid >> 2;
    const int sa_k4  = (tid & 3) * 4;
    const int sa_ng  = min(n_base + sa_row, N - 1);
    const float scA1 = s1 ? s1[sa_ng] : 1.0f;
    const int sb_c = tid & 127;
    const int sb_h = (tid >> 7) * 16;
    const int lane = tid & 63, wv = tid >> 6;
    const int fr = lane & 15;
    const int fk = (lane >> 4) * 8;

    f32x4 acc[8];
#pragma unroll
    for (int t = 0; t < 8; ++t) acc[t] = (f32x4){0.f, 0.f, 0.f, 0.f};

    const int nsteps = K >> 5;
    for (int s = 0; s < nsteps; ++s) {
        const int k0 = s * 32;
        __syncthreads();
        const float* Ab; int kof; float sc;
        if (K == 256 && k0 >= 128) { Ab = A1; kof = k0 - 128; sc = scA1; }
        else                       { Ab = A0; kof = k0;       sc = 1.0f; }
#pragma unroll
        for (int ch = 0; ch < 32; ch += 16) {
            float4 v = *reinterpret_cast<const float4*>(
                Ab + (size_t)sa_ng * HD + kof + ch + sa_k4);
            float vv[4] = {v.x * sc, v.y * sc, v.z * sc, v.w * sc};
            ushort4 hi, lo;
            hi.x = f2bf(vv[0]); lo.x = f2bf(vv[0] - bf2f(hi.x));
            hi.y = f2bf(vv[1]); lo.y = f2bf(vv[1] - bf2f(hi.y));
            hi.z = f2bf(vv[2]); lo.z = f2bf(vv[2] - bf2f(hi.z));
            hi.w = f2bf(vv[3]); lo.w = f2bf(vv[3] - bf2f(hi.w));
            *reinterpret_cast<ushort4*>(&Ahi_s[sa_row][ch + sa_k4]) = hi;
            *reinterpret_cast<ushort4*>(&Alo_s[sa_row][ch + sa_k4]) = lo;
        }
        {
            const ushort* ph = WT_hi + (size_t)sb_c * wstride + kw0 + k0 + sb_h;
            const ushort* pl = WT_lo + (size_t)sb_c * wstride + kw0 + k0 + sb_h;
            *reinterpret_cast<uint4*>(&Bhi_s[sb_c][sb_h])     = *reinterpret_cast<const uint4*>(ph);
            *reinterpret_cast<uint4*>(&Bhi_s[sb_c][sb_h + 8]) = *reinterpret_cast<const uint4*>(ph + 8);
            *reinterpret_cast<uint4*>(&Blo_s[sb_c][sb_h])     = *reinterpret_cast<const uint4*>(pl);
            *reinterpret_cast<uint4*>(&Blo_s[sb_c][sb_h + 8]) = *reinterpret_cast<const uint4*>(pl + 8);
        }
        __syncthreads();
        bf16x8 ah = *reinterpret_cast<bf16x8*>(&Ahi_s[wv * 16 + fr][fk]);
        bf16x8 al = *reinterpret_cast<bf16x8*>(&Alo_s[wv * 16 + fr][fk]);
#pragma unroll
        for (int t = 0; t < 8; ++t) {
            bf16x8 bh = *reinterpret_cast<bf16x8*>(&Bhi_s[t * 16 + fr][fk]);
            bf16x8 bl = *reinterpret_cast<bf16x8*>(&Blo_s[t * 16 + fr][fk]);
            acc[t] = __builtin_amdgcn_mfma_f32_16x16x32_bf16(ah, bh, acc[t], 0, 0, 0);
            acc[t] = __builtin_amdgcn_mfma_f32_16x16x32_bf16(al, bh, acc[t], 0, 0, 0);
            acc[t] = __builtin_amdgcn_mfma_f32_16x16x32_bf16(ah, bl, acc[t], 0, 0, 0);
        }
    }
#pragma unroll
    for (int reg = 0; reg < 4; ++reg) {
        int n = n_base + wv * 16 + (lane >> 4) * 4 + reg;
        if (n < N) {
            float bs = bscale ? bscale[n] : 1.0f;
#pragma unroll
            for (int t = 0; t < 8; ++t) {
                int c = t * 16 + fr;
                float v = acc[t][reg] + (bias ? bias[c] * bs : 0.0f);
                out[(size_t)n * HD + c] = relu ? fmaxf(v, 0.0f) : v;
            }
        }
    }
}

// ---------------- node head ----------------
__global__ __launch_bounds__(256) void node_head_kernel(
    const float* __restrict__ h,
    const float* __restrict__ W1, const float* __restrict__ b1,
    const float* __restrict__ W2, const float* __restrict__ b2,
    float* __restrict__ out, int N)
{
    int n = blockIdx.x * 4 + (threadIdx.x >> 6);
    int lane = threadIdx.x & 63;
    if (n >= N) return;
    const float* hr = h + (size_t)n * HD;
    float t = b1[lane];
#pragma unroll 16
    for (int k = 0; k < HD; ++k)
        t = fmaf(hr[k], W1[k * 64 + lane], t);
    t = fmaxf(t, 0.0f);
    float o0 = t * W2[lane * 2 + 0];
    float o1 = t * W2[lane * 2 + 1];
#pragma unroll
    for (int sft = 32; sft > 0; sft >>= 1) {
        o0 += __shfl_xor(o0, sft);
        o1 += __shfl_xor(o1, sft);
    }
    if (lane == 0) {
        out[(size_t)n * 2 + 0] = o0 + b2[0];
        out[(size_t)n * 2 + 1] = o1 + b2[1];
    }
}

// ---------------- fused edge head, CSR-ordered, all-register t1, deep ILP ----------------
// __launch_bounds__(256,2): allow up to 256 VGPR so all 16 P/Q gathers fly at once.
__global__ __launch_bounds__(256, 2) void edge_head_kernel(
    const float* __restrict__ P, const float* __restrict__ Q,
    const int* __restrict__ csr_src, const int* __restrict__ csr_dst,
    const int* __restrict__ csr_eid,
    const float* __restrict__ ea,
    const float* __restrict__ W1c, const float* __restrict__ b1,
    const ushort* __restrict__ W2Th, const ushort* __restrict__ W2Tl,  // [64][128]
    const float* __restrict__ b2,
    const float* __restrict__ W3, const float* __restrict__ b3,
    float* __restrict__ out, int E)
{
    const int tid  = threadIdx.x;
    const int base = blockIdx.x * 64;
    const int lane = tid & 63, wv = tid >> 6;
    const int fr = lane & 15;          // edge within wave-tile / output col idx
    const int hi16 = lane >> 4;        // 0..3
    const int fk = hi16 * 8;           // k-offset within 32-chunk

    const int slot = min(base + wv * 16 + fr, E - 1);
    const int sn  = csr_src[slot];
    const int dn  = csr_dst[slot];
    const int eid = csr_eid[slot];

    // ---- issue ALL gathers up front (16 x float4 + 2 x float4) ----
    const float* Pr = P + (size_t)sn * HD;
    const float* Qr = Q + (size_t)dn * HD;
    float4 pb[8], qb[8];
#pragma unroll
    for (int kt = 0; kt < 4; ++kt) {
        const int c0 = kt * 32 + fk;
        pb[2 * kt]     = *reinterpret_cast<const float4*>(Pr + c0);
        pb[2 * kt + 1] = *reinterpret_cast<const float4*>(Pr + c0 + 4);
        qb[2 * kt]     = *reinterpret_cast<const float4*>(Qr + c0);
        qb[2 * kt + 1] = *reinterpret_cast<const float4*>(Qr + c0 + 4);
    }
    float4 e0 = *reinterpret_cast<const float4*>(ea + (size_t)eid * 8);
    float4 e1 = *reinterpret_cast<const float4*>(ea + (size_t)eid * 8 + 4);
    float eav[8] = {e0.x, e0.y, e0.z, e0.w, e1.x, e1.y, e1.z, e1.w};

    // ---- phase 1: t1 = relu(P+Q+b1 + ea@W1c) -> split-bf16 A frags ----
    bf16x8 ah[4], al[4];
#pragma unroll
    for (int kt = 0; kt < 4; ++kt) {
        const int c0 = kt * 32 + fk;
        float4 b0 = *reinterpret_cast<const float4*>(b1 + c0);
        float4 b1v = *reinterpret_cast<const float4*>(b1 + c0 + 4);
        float4 p0 = pb[2 * kt], p1 = pb[2 * kt + 1];
        float4 q0 = qb[2 * kt], q1 = qb[2 * kt + 1];
        float v[8];
        v[0] = p0.x + q0.x + b0.x;  v[1] = p0.y + q0.y + b0.y;
        v[2] = p0.z + q0.z + b0.z;  v[3] = p0.w + q0.w + b0.w;
        v[4] = p1.x + q1.x + b1v.x; v[5] = p1.y + q1.y + b1v.y;
        v[6] = p1.z + q1.z + b1v.z; v[7] = p1.w + q1.w + b1v.w;
#pragma unroll
        for (int k = 0; k < 8; ++k) {
            float4 w0 = *reinterpret_cast<const float4*>(W1c + k * HD + c0);
            float4 w1 = *reinterpret_cast<const float4*>(W1c + k * HD + c0 + 4);
            v[0] = fmaf(eav[k], w0.x, v[0]); v[1] = fmaf(eav[k], w0.y, v[1]);
            v[2] = fmaf(eav[k], w0.z, v[2]); v[3] = fmaf(eav[k], w0.w, v[3]);
            v[4] = fmaf(eav[k], w1.x, v[4]); v[5] = fmaf(eav[k], w1.y, v[5]);
            v[6] = fmaf(eav[k], w1.z, v[6]); v[7] = fmaf(eav[k], w1.w, v[7]);
        }
#pragma unroll
        for (int j = 0; j < 8; ++j) {
            float t = fmaxf(v[j], 0.0f);
            ushort h = f2bf(t);
            ushort l = f2bf(t - bf2f(h));
            ah[kt][j] = (short)h;
            al[kt][j] = (short)l;
        }
    }

    // ---- phase 2: t2 = t1 @ W2 via MFMA (B frags from L2) ----
    f32x4 acc[4];
#pragma unroll
    for (int t = 0; t < 4; ++t) acc[t] = (f32x4){0.f, 0.f, 0.f, 0.f};
#pragma unroll
    for (int kt = 0; kt < 4; ++kt) {
#pragma unroll
        for (int t = 0; t < 4; ++t) {
            const size_t boff = (size_t)(t * 16 + fr) * 128 + kt * 32 + fk;
            bf16x8 bh = *reinterpret_cast<const bf16x8*>(W2Th + boff);
            bf16x8 bl = *reinterpret_cast<const bf16x8*>(W2Tl + boff);
            acc[t] = __builtin_amdgcn_mfma_f32_16x16x32_bf16(ah[kt], bh, acc[t], 0, 0, 0);
            acc[t] = __builtin_amdgcn_mfma_f32_16x16x32_bf16(al[kt], bh, acc[t], 0, 0, 0);
            acc[t] = __builtin_amdgcn_mfma_f32_16x16x32_bf16(ah[kt], bl, acc[t], 0, 0, 0);
        }
    }

    // ---- phase 3: out = relu(t2+b2) @ W3 + b3, in registers ----
    float b2v[4];
#pragma unroll
    for (int t = 0; t < 4; ++t) b2v[t] = b2[t * 16 + fr];
#pragma unroll
    for (int reg = 0; reg < 4; ++reg) {
        int erow = wv * 16 + hi16 * 4 + reg;
        float p[6];
#pragma unroll
        for (int j = 0; j < 6; ++j) p[j] = 0.0f;
#pragma unroll
        for (int t = 0; t < 4; ++t) {
            int c = t * 16 + fr;
            float t2v = fmaxf(acc[t][reg] + b2v[t], 0.0f);
#pragma unroll
            for (int j = 0; j < 6; ++j)
                p[j] = fmaf(t2v, W3[c * 6 + j], p[j]);
        }
#pragma unroll
        for (int j = 0; j < 6; ++j) {
#pragma unroll
            for (int sft = 1; sft < 16; sft <<= 1)
                p[j] += __shfl_xor(p[j], sft);
        }
        int oslot = base + erow;
        if (fr < 6 && oslot < E) {
            int oeid = csr_eid[oslot];
            out[(size_t)oeid * 6 + fr] = p[fr] + b3[fr];
        }
    }
}

// ---------------- launch ----------------
extern "C" void kernel_launch(void* const* d_in, const int* in_sizes, int n_in,
                              void* d_out, int out_size, void* d_ws, size_t ws_size,
                              hipStream_t stream)
{
    (void)n_in; (void)out_size; (void)ws_size;
    const float* x     = (const float*)d_in[0];
    const int*   ei    = (const int*)d_in[1];
    const float* eattr = (const float*)d_in[2];
    const float* Wenc = (const float*)d_in[4];
    const float* benc = (const float*)d_in[5];
    const float* Wmsg = (const float*)d_in[6];
    const float* bmsg = (const float*)d_in[7];
    const float* Wupd = (const float*)d_in[8];
    const float* bupd = (const float*)d_in[9];
    const float* Wn1  = (const float*)d_in[10];
    const float* bn1  = (const float*)d_in[11];
    const float* Wn2  = (const float*)d_in[12];
    const float* bn2  = (const float*)d_in[13];
    const float* We1  = (const float*)d_in[14];
    const float* be1  = (const float*)d_in[15];
    const float* We2  = (const float*)d_in[16];
    const float* be2  = (const float*)d_in[17];
    const float* We3  = (const float*)d_in[18];
    const float* be3  = (const float*)d_in[19];

    const int N = in_sizes[0] / 16;
    const int E = in_sizes[1] / 2;
    const int* src = ei;
    const int* dst = ei + E;

    float* h0   = (float*)d_ws;
    float* h1   = h0 + (size_t)N * HD;
    float* S    = h1 + (size_t)N * HD;     // pull target; later reused as P
    float* Qb   = S  + (size_t)N * HD;     // later Q
    float* rs   = Qb + (size_t)N * HD;
    float* ss   = rs + N;
    int* deg_i  = (int*)(ss + N);
    int* off    = deg_i + N;               // N+1
    int* cursor = off + N + 1;
    int* csr_s  = cursor + N;              // E
    int* csr_d  = csr_s + E;               // E
    int* csr_e  = csr_d + E;               // E
    float* fM   = (float*)(((uintptr_t)(csr_e + E) + 255) & ~(uintptr_t)255);
    float* M12  = fM;                      // 256*128
    float* cvec = fM + 32768;              // 128
    ushort* wt  = (ushort*)(cvec + 128);
    ushort* wft_hi = wt;                   // 128*384
    ushort* wft_lo = wft_hi + 49152;
    ushort* wte_hi = wft_lo + 49152;       // 128*256
    ushort* wte_lo = wte_hi + 32768;
    ushort* w2t_hi = wte_lo + 32768;       // 64*128
    ushort* w2t_lo = w2t_hi + 8192;

    float* node_out = (float*)d_out;
    float* edge_out = node_out + (size_t)N * 2;

    // ---- CSR build ----
    hipMemsetAsync(deg_i, 0, (size_t)N * sizeof(int), stream);
    hipMemsetAsync(cursor, 0, (size_t)N * sizeof(int), stream);
    deg_int_kernel<<<(E + 255) / 256, 256, 0, stream>>>(dst, deg_i, E);
    scan_kernel<<<1, 1024, 0, stream>>>(deg_i, off, N);
    degscale_kernel<<<(N + 255) / 256, 256, 0, stream>>>(deg_i, rs, ss, N);
    csr_fill_kernel<<<(E + 255) / 256, 256, 0, stream>>>(
        src, dst, off, cursor, csr_s, csr_d, csr_e, E);

    // ---- fused-weight precompute (exact f32) + bf16 hi/lo conversion ----
    mm2_kernel<<<256, 128, 0, stream>>>(Wmsg, Wupd, M12);
    cvec_kernel<<<1, 128, 0, stream>>>(bmsg, Wupd, cvec);
    wft_build_kernel<<<192, 256, 0, stream>>>(Wupd, M12, wft_hi, wft_lo);
    wt_convert_kernel<<<128, 256, 0, stream>>>(We1, wte_hi, wte_lo, 256, 128);
    wt_convert_kernel<<<32,  256, 0, stream>>>(We2, w2t_hi, w2t_lo, 128, 64);

    // ---- encoder ----
    encoder_kernel<<<(N + 1) / 2, 256, 0, stream>>>(x, Wenc, benc, h0, N);

    // ---- GNN layers: pull + ONE fused GEMM per layer ----
    const int gblocks = (N + 63) / 64;
    float* hc = h0;
    float* hn = h1;
    for (int l = 0; l < 3; ++l) {
        pull_kernel<<<(N + 3) / 4, 256, 0, stream>>>(hc, off, csr_s, rs, S, N);
        gemm_fused_kernel<<<gblocks, 256, 0, stream>>>(
            hc, S, ss, wft_hi, wft_lo, bupd, cvec, hn, N);
        float* t = hc; hc = hn; hn = t;
    }

    // ---- P/Q precompute for edge head ----
    float* Pb = S;
    gemm_mfma_kernel<<<gblocks, 256, 0, stream>>>(
        hc, nullptr, nullptr, wte_hi, wte_lo, 256, 0, nullptr, nullptr, Pb, N, 128, 0);
    gemm_mfma_kernel<<<gblocks, 256, 0, stream>>>(
        hc, nullptr, nullptr, wte_hi, wte_lo, 256, 128, nullptr, nullptr, Qb, N, 128, 0);

    // ---- heads ----
    node_head_kernel<<<(N + 3) / 4, 256, 0, stream>>>(
        hc, Wn1, bn1, Wn2, bn2, node_out, N);
    edge_head_kernel<<<(E + 63) / 64, 256, 0, stream>>>(
        Pb, Qb, csr_s, csr_d, csr_e, eattr, We1 + (size_t)256 * HD, be1,
        w2t_hi, w2t_lo, be2, We3, be3, edge_out, E);
}